// Round 2
// baseline (678.659 us; speedup 1.0000x reference)
//
#include <hip/hip_runtime.h>
#include <hip/hip_bf16.h>
#include <stdint.h>

// GAT-style attention layer, B=4 N=4096 Din=256 Dout=128, fp32 in/out.
// Pipeline:
//  k1: h = x@W (fp32), store hT (fp16, [b][d][n]) + Wh1/Wh2 = h@a (fp32)
//  k2: per-column S_j = sum_i mask * exp(gelu(Wh1_i+Wh2_j)); compress adj -> bitmask
//  k25: Sinv = 1/S
//  k3: out_pre[i,d] = sum_j P(i,j) h[j,d]; P generated in-register, split into
//      fp16 hi+lo (2 MFMAs) so only h's fp16 rounding (2^-11) remains
//  k4a: gelu + column sum-of-squares; k4b: L2-normalize over i + bias

#define NN   4096
#define BB   4
#define DIN  256
#define DOUT 128

typedef unsigned short u16;
typedef _Float16 f16x8 __attribute__((ext_vector_type(8)));
typedef __attribute__((ext_vector_type(4))) float f32x4;

__device__ __forceinline__ u16 f2h_bits(float f) {
  _Float16 h = (_Float16)f;          // v_cvt_f16_f32, RNE
  union { _Float16 h; u16 u; } v; v.h = h;
  return v.u;
}

// Abramowitz-Stegun 7.1.26, |err| < 1.5e-7
__device__ __forceinline__ float erf_f(float x) {
  float ax = __builtin_fabsf(x);
  float t  = __builtin_amdgcn_rcpf(__builtin_fmaf(0.3275911f, ax, 1.0f));
  float p  = __builtin_fmaf(1.061405429f, t, -1.453152027f);
  p = __builtin_fmaf(p, t, 1.421413741f);
  p = __builtin_fmaf(p, t, -0.284496736f);
  p = __builtin_fmaf(p, t, 0.254829592f);
  p = p * t;
  float e  = __expf(-ax * ax);
  float er = __builtin_fmaf(-p, e, 1.0f);
  return copysignf(er, x);
}

__device__ __forceinline__ float gelu_f(float z) {
  float hz = 0.5f * z;
  return __builtin_fmaf(hz, erf_f(z * 0.70710678118654752f), hz);
}

__device__ __forceinline__ float exp_gelu(float z) { return __expf(gelu_f(z)); }

// ---------------- k1: h = x@W, Wh1/Wh2, hT(fp16) ----------------
// grid (NN/32, BB), block 256.  32 rows/block; thread = (dgrp 0..31, rgrp 0..7),
// 4 d x 4 rows register tile.
__global__ __launch_bounds__(256, 2) void k1_proj(
    const float* __restrict__ x, const float* __restrict__ weight,
    const float* __restrict__ a, u16* __restrict__ hT,
    float* __restrict__ Wh1, float* __restrict__ Wh2)
{
  __shared__ float xs[32 * 256];     // 32 KB
  __shared__ float T[128 * 33];      // padded transpose buffer (16.9 KB)
  __shared__ float P2a[8 * 32], P2b[8 * 32];

  const int b = blockIdx.y, n0 = blockIdx.x * 32;
  const int tid = threadIdx.x;

  // stage x tile (32 rows x 256)
  const float4* xsrc = (const float4*)(x + ((size_t)b * NN + n0) * DIN);
  float4* xd = (float4*)xs;
#pragma unroll
  for (int v = 0; v < 8; ++v) xd[tid + v * 256] = xsrc[tid + v * 256];
  __syncthreads();

  const int dg = tid & 31, rg = tid >> 5;
  float acc[4][4] = {};
  const float4* W4 = (const float4*)weight;
#pragma unroll 4
  for (int k = 0; k < 256; ++k) {
    float4 wr = W4[k * 32 + dg];
#pragma unroll
    for (int rr = 0; rr < 4; ++rr) {
      float xv = xs[(rg * 4 + rr) * 256 + k];
      acc[rr][0] = fmaf(xv, wr.x, acc[rr][0]);
      acc[rr][1] = fmaf(xv, wr.y, acc[rr][1]);
      acc[rr][2] = fmaf(xv, wr.z, acc[rr][2]);
      acc[rr][3] = fmaf(xv, wr.w, acc[rr][3]);
    }
  }
  // transpose h into T[d][r]
#pragma unroll
  for (int rr = 0; rr < 4; ++rr)
#pragma unroll
    for (int dd = 0; dd < 4; ++dd)
      T[(dg * 4 + dd) * 33 + rg * 4 + rr] = acc[rr][dd];
  __syncthreads();

  // hT fp16 store: thread = (d 0..127, half 0..1), 16 values each
  {
    const int d = tid & 127, half = tid >> 7;
    unsigned int uu[8];
#pragma unroll
    for (int p = 0; p < 8; ++p) {
      float f0 = T[d * 33 + half * 16 + p * 2];
      float f1 = T[d * 33 + half * 16 + p * 2 + 1];
      uu[p] = (unsigned int)f2h_bits(f0) | ((unsigned int)f2h_bits(f1) << 16);
    }
    u16* dst = hT + ((size_t)b * DOUT + d) * NN + n0 + half * 16;
    ((uint4*)dst)[0] = make_uint4(uu[0], uu[1], uu[2], uu[3]);
    ((uint4*)dst)[1] = make_uint4(uu[4], uu[5], uu[6], uu[7]);
  }
  // Wh1/Wh2 partials: thread = (r 0..31, g8 0..7), 16 d each
  {
    const int r = tid & 31, g8 = tid >> 5;
    float p1 = 0.f, p2 = 0.f;
#pragma unroll
    for (int q = 0; q < 16; ++q) {
      int d = g8 * 16 + q;
      float hv = T[d * 33 + r];
      p1 = fmaf(hv, a[d], p1);
      p2 = fmaf(hv, a[DOUT + d], p2);
    }
    P2a[g8 * 32 + r] = p1;
    P2b[g8 * 32 + r] = p2;
  }
  __syncthreads();
  if (tid < 32) {
    float s1 = 0.f, s2 = 0.f;
#pragma unroll
    for (int g8 = 0; g8 < 8; ++g8) { s1 += P2a[g8 * 32 + tid]; s2 += P2b[g8 * 32 + tid]; }
    Wh1[b * NN + n0 + tid] = s1;
    Wh2[b * NN + n0 + tid] = s2;
  }
}

// ---------------- k2: column sums S_j + adj -> bitmask ----------------
// grid (16 jtiles, 16 ichunks, BB), block 256 (one column j per thread,
// 256 rows per chunk, register accumulation, one atomicAdd at the end).
__global__ __launch_bounds__(256, 2) void k2_colsum(
    const int* __restrict__ adj, const float* __restrict__ Wh1,
    const float* __restrict__ Wh2, float* __restrict__ S,
    unsigned long long* __restrict__ mask64)
{
  const int b = blockIdx.z, jt = blockIdx.x, ic = blockIdx.y;
  const int tid = threadIdx.x;
  const int j = jt * 256 + tid;
  const int i0 = ic * 256;
  const int lane = tid & 63, wv = tid >> 6;

  const float wh2 = Wh2[b * NN + j];
  const int* ap = adj + ((size_t)b * NN + i0) * NN + j;
  const float* w1p = Wh1 + b * NN + i0;
  unsigned long long* mrow = mask64 + ((size_t)b * NN + i0) * 64 + (jt * 4 + wv);

  float s = 0.f;
#pragma unroll 8
  for (int ii = 0; ii < 256; ++ii) {
    int av = ap[(size_t)ii * NN];
    float w1 = w1p[ii];                      // uniform -> scalar load
    float E = exp_gelu(w1 + wh2);
    bool mbit = av > 0;
    unsigned long long bal = __ballot(mbit);
    if (lane == 0) mrow[(size_t)ii * 64] = bal;
    s += mbit ? E : 0.f;
  }
  atomicAdd(&S[b * NN + j], s);
}

__global__ __launch_bounds__(256) void k25_rcp(const float* __restrict__ S,
                                               float* __restrict__ Sinv)
{
  int id = blockIdx.x * 256 + threadIdx.x;
  Sinv[id] = 1.0f / S[id];     // all-masked column cannot occur (p=0.5, N=4096)
}

// ---------------- k3: out_pre = P @ h via fp16 MFMA, P split hi+lo ----------------
// grid (NN/32, BB), block 256 = 4 waves: wave = (strip s in {0,1}, khalf h in {0,1}).
// Strip = 16 rows; A-frag (P) generated in-register; B (hT fp16) staged in LDS.
__global__ __launch_bounds__(256, 2) void k3_attn(
    const unsigned char* __restrict__ maskb, const float* __restrict__ Wh1,
    const float* __restrict__ Wh2, const float* __restrict__ Sinv,
    const u16* __restrict__ hT, float* __restrict__ out_pre)
{
  __shared__ __align__(16) u16 tile[2][128][72];   // [khalf][d][64 k + 8 pad] = 36.9 KB

  const int b = blockIdx.y;
  const int tid = threadIdx.x;
  const int wv = tid >> 6, lane = tid & 63;
  const int s = wv & 1, h = wv >> 1;
  const int i_base = blockIdx.x * 32 + s * 16;
  const int m = lane & 15, quad = lane >> 4;
  const int i = i_base + m;

  const float w1 = Wh1[b * NN + i];
  const unsigned char* mrow = maskb + ((size_t)b * NN + i) * 512;
  const u16* hTb = hT + (size_t)b * DOUT * NN;

  f32x4 acc[8];
#pragma unroll
  for (int t = 0; t < 8; ++t) acc[t] = (f32x4){0.f, 0.f, 0.f, 0.f};

  const int sd = tid & 127, ch = tid >> 7;
  const u16* src0 = hTb + (size_t)sd * NN + ch * 2048;

  for (int c = 0; c < 32; ++c) {
    __syncthreads();
    {
      const u16* src = src0 + c * 64;
#pragma unroll
      for (int g = 0; g < 8; ++g)
        *(uint4*)&tile[ch][sd][g * 8] = *(const uint4*)(src + g * 8);
    }
    __syncthreads();
#pragma unroll
    for (int ks = 0; ks < 2; ++ks) {
      const int j0 = h * 2048 + c * 64 + ks * 32;
      const int jq = j0 + quad * 8;
      const float4* wp = (const float4*)(Wh2 + b * NN + jq);
      float4 w2a = wp[0], w2b = wp[1];
      const float4* sp = (const float4*)(Sinv + b * NN + jq);
      float4 sva = sp[0], svb = sp[1];
      unsigned int mb = mrow[(j0 >> 3) + quad];

      float p0 = (mb & 1u)   ? exp_gelu(w1 + w2a.x) * sva.x : 0.f;
      float p1 = (mb & 2u)   ? exp_gelu(w1 + w2a.y) * sva.y : 0.f;
      float p2 = (mb & 4u)   ? exp_gelu(w1 + w2a.z) * sva.z : 0.f;
      float p3 = (mb & 8u)   ? exp_gelu(w1 + w2a.w) * sva.w : 0.f;
      float p4 = (mb & 16u)  ? exp_gelu(w1 + w2b.x) * svb.x : 0.f;
      float p5 = (mb & 32u)  ? exp_gelu(w1 + w2b.y) * svb.y : 0.f;
      float p6 = (mb & 64u)  ? exp_gelu(w1 + w2b.z) * svb.z : 0.f;
      float p7 = (mb & 128u) ? exp_gelu(w1 + w2b.w) * svb.w : 0.f;

      // fp16 hi + lo split of P: residual quantization ~2^-22
      f16x8 ah, al;
      float q[8] = {p0, p1, p2, p3, p4, p5, p6, p7};
#pragma unroll
      for (int e = 0; e < 8; ++e) {
        _Float16 hi = (_Float16)q[e];
        ah[e] = hi;
        al[e] = (_Float16)(q[e] - (float)hi);
      }

#pragma unroll
      for (int t = 0; t < 8; ++t) {
        f16x8 bf = *(const f16x8*)&tile[h][t * 16 + m][ks * 32 + quad * 8];
        acc[t] = __builtin_amdgcn_mfma_f32_16x16x32_f16(ah, bf, acc[t], 0, 0, 0);
        acc[t] = __builtin_amdgcn_mfma_f32_16x16x32_f16(al, bf, acc[t], 0, 0, 0);
      }
    }
  }

  // reduce the two K-halves per strip, then store (C layout: row=quad*4+reg, col=lane&15)
  __syncthreads();
  float* red = (float*)&tile[0][0][0];   // 16 KB needed, 36.9 KB available
  if (h == 1) {
#pragma unroll
    for (int t = 0; t < 8; ++t)
#pragma unroll
      for (int r = 0; r < 4; ++r)
        red[(t * 4 + r) * 128 + s * 64 + lane] = acc[t][r];
  }
  __syncthreads();
  if (h == 0) {
#pragma unroll
    for (int t = 0; t < 8; ++t) {
#pragma unroll
      for (int r = 0; r < 4; ++r) {
        float v = acc[t][r] + red[(t * 4 + r) * 128 + s * 64 + lane];
        out_pre[((size_t)b * NN + i_base + quad * 4 + r) * DOUT + t * 16 + m] = v;
      }
    }
  }
}

// ---------------- k4a: gelu + column sum-of-squares ----------------
__global__ __launch_bounds__(256) void k4a_gelu_norm(
    const float* __restrict__ out_pre, float* __restrict__ gout,
    float* __restrict__ norm2)
{
  __shared__ float pbuf[256];
  const int b = blockIdx.y;
  const int i0 = blockIdx.x * 64;
  const int tid = threadIdx.x;
  const int d = tid & 127, rh = tid >> 7;
  float acc = 0.f;
  for (int ii = rh; ii < 64; ii += 2) {
    size_t idx = ((size_t)b * NN + i0 + ii) * DOUT + d;
    float g = gelu_f(out_pre[idx]);
    gout[idx] = g;
    acc = fmaf(g, g, acc);
  }
  pbuf[tid] = acc;
  __syncthreads();
  if (tid < 128) atomicAdd(&norm2[b * DOUT + tid], pbuf[tid] + pbuf[tid + 128]);
}

// ---------------- k4b: scale by 1/max(||col||,1e-12) + bias ----------------
__global__ __launch_bounds__(256) void k4b_scale(
    float* __restrict__ out, const float* __restrict__ norm2,
    const float* __restrict__ bias)
{
  int id = blockIdx.x * 256 + threadIdx.x;
  int d = id & 127;
  int b = id >> 19;                        // N*DOUT = 2^19 per batch
  float nrm = sqrtf(norm2[b * DOUT + d]);
  float sc = 1.0f / fmaxf(nrm, 1e-12f);
  out[id] = fmaf(out[id], sc, bias[d]);
}

extern "C" void kernel_launch(void* const* d_in, const int* in_sizes, int n_in,
                              void* d_out, int out_size, void* d_ws, size_t ws_size,
                              hipStream_t stream)
{
  const float* x      = (const float*)d_in[0];
  const int*   adj    = (const int*)d_in[1];
  const float* weight = (const float*)d_in[2];
  const float* a      = (const float*)d_in[3];
  const float* bias   = (const float*)d_in[4];
  float* out = (float*)d_out;

  // workspace layout (all 16B aligned), ~21.3 MB total
  char* ws = (char*)d_ws;
  u16*   hT     = (u16*)ws;                                    // 4 MB
  float* Wh1    = (float*)(ws + (size_t)4 * 1024 * 1024);      // 64 KB
  float* Wh2    = Wh1 + BB * NN;                               // 64 KB
  float* S      = Wh2 + BB * NN;                               // 64 KB
  float* Sinv   = S + BB * NN;                                 // 64 KB
  unsigned long long* mask64 = (unsigned long long*)(Sinv + BB * NN);  // 8 MB
  float* out_pre = (float*)((char*)mask64 + (size_t)BB * NN * 64 * 8); // 8 MB
  float* norm2   = out_pre + (size_t)BB * NN * DOUT;           // 2 KB

  hipMemsetAsync(S, 0, (size_t)BB * NN * sizeof(float), stream);
  hipMemsetAsync(norm2, 0, (size_t)BB * DOUT * sizeof(float), stream);

  k1_proj<<<dim3(NN / 32, BB), 256, 0, stream>>>(x, weight, a, hT, Wh1, Wh2);
  k2_colsum<<<dim3(16, 16, BB), 256, 0, stream>>>(adj, Wh1, Wh2, S, mask64);
  k25_rcp<<<dim3(BB * NN / 256), 256, 0, stream>>>(S, Sinv);
  k3_attn<<<dim3(NN / 32, BB), 256, 0, stream>>>((const unsigned char*)mask64,
                                                 Wh1, Wh2, Sinv, hT, out_pre);
  k4a_gelu_norm<<<dim3(64, BB), 256, 0, stream>>>(out_pre, out, norm2);
  k4b_scale<<<dim3((BB * NN * DOUT) / 256), 256, 0, stream>>>(out, norm2, bias);
}

// Round 3
// 625.586 us; speedup vs baseline: 1.0848x; 1.0848x over previous
//
#include <hip/hip_runtime.h>
#include <hip/hip_bf16.h>
#include <stdint.h>

// GAT-style attention layer, B=4 N=4096 Din=256 Dout=128, fp32 in/out.
// Pipeline:
//  k1 : h = x@W (fp32), store hT (fp16, [b][d][n]) + Wh1/Wh2 = h@a (fp32)
//  k2a: adj -> bitmask (pure stream, 268 MB read once)
//  k2b: per-column S_j = sum_i mask*exp(gelu(Wh1_i+Wh2_j)) from bitmask (VALU-bound)
//  k25: Sinv = 1/S
//  k3 : out_pre[i,d] = sum_j P(i,j) h[j,d]; P generated in-register, fp16 hi+lo
//  k4a: gelu + column sum-of-squares; k4b: L2-normalize over i + bias

#define NN   4096
#define BB   4
#define DIN  256
#define DOUT 128

typedef unsigned short u16;
typedef _Float16 f16x8 __attribute__((ext_vector_type(8)));
typedef __attribute__((ext_vector_type(4))) float f32x4;

__device__ __forceinline__ u16 f2h_bits(float f) {
  _Float16 h = (_Float16)f;          // v_cvt_f16_f32, RNE
  union { _Float16 h; u16 u; } v; v.h = h;
  return v.u;
}

// Abramowitz-Stegun 7.1.26, |err| < 1.5e-7
__device__ __forceinline__ float erf_f(float x) {
  float ax = __builtin_fabsf(x);
  float t  = __builtin_amdgcn_rcpf(__builtin_fmaf(0.3275911f, ax, 1.0f));
  float p  = __builtin_fmaf(1.061405429f, t, -1.453152027f);
  p = __builtin_fmaf(p, t, 1.421413741f);
  p = __builtin_fmaf(p, t, -0.284496736f);
  p = __builtin_fmaf(p, t, 0.254829592f);
  p = p * t;
  float e  = __expf(-ax * ax);
  float er = __builtin_fmaf(-p, e, 1.0f);
  return copysignf(er, x);
}

__device__ __forceinline__ float gelu_f(float z) {
  float hz = 0.5f * z;
  return __builtin_fmaf(hz, erf_f(z * 0.70710678118654752f), hz);
}

__device__ __forceinline__ float exp_gelu(float z) { return __expf(gelu_f(z)); }

// ---------------- k1: h = x@W, Wh1/Wh2, hT(fp16) ----------------
// grid (NN/32, BB), block 256.  32 rows/block; thread = (dgrp 0..31, rgrp 0..7),
// 4 d x 4 rows register tile.
__global__ __launch_bounds__(256, 2) void k1_proj(
    const float* __restrict__ x, const float* __restrict__ weight,
    const float* __restrict__ a, u16* __restrict__ hT,
    float* __restrict__ Wh1, float* __restrict__ Wh2)
{
  __shared__ float xs[32 * 256];     // 32 KB
  __shared__ float T[128 * 33];      // padded transpose buffer (16.9 KB)
  __shared__ float P2a[8 * 32], P2b[8 * 32];

  const int b = blockIdx.y, n0 = blockIdx.x * 32;
  const int tid = threadIdx.x;

  // stage x tile (32 rows x 256)
  const float4* xsrc = (const float4*)(x + ((size_t)b * NN + n0) * DIN);
  float4* xd = (float4*)xs;
#pragma unroll
  for (int v = 0; v < 8; ++v) xd[tid + v * 256] = xsrc[tid + v * 256];
  __syncthreads();

  const int dg = tid & 31, rg = tid >> 5;
  float acc[4][4] = {};
  const float4* W4 = (const float4*)weight;
#pragma unroll 4
  for (int k = 0; k < 256; ++k) {
    float4 wr = W4[k * 32 + dg];
#pragma unroll
    for (int rr = 0; rr < 4; ++rr) {
      float xv = xs[(rg * 4 + rr) * 256 + k];
      acc[rr][0] = fmaf(xv, wr.x, acc[rr][0]);
      acc[rr][1] = fmaf(xv, wr.y, acc[rr][1]);
      acc[rr][2] = fmaf(xv, wr.z, acc[rr][2]);
      acc[rr][3] = fmaf(xv, wr.w, acc[rr][3]);
    }
  }
  // transpose h into T[d][r]
#pragma unroll
  for (int rr = 0; rr < 4; ++rr)
#pragma unroll
    for (int dd = 0; dd < 4; ++dd)
      T[(dg * 4 + dd) * 33 + rg * 4 + rr] = acc[rr][dd];
  __syncthreads();

  // hT fp16 store: thread = (d 0..127, half 0..1), 16 values each
  {
    const int d = tid & 127, half = tid >> 7;
    unsigned int uu[8];
#pragma unroll
    for (int p = 0; p < 8; ++p) {
      float f0 = T[d * 33 + half * 16 + p * 2];
      float f1 = T[d * 33 + half * 16 + p * 2 + 1];
      uu[p] = (unsigned int)f2h_bits(f0) | ((unsigned int)f2h_bits(f1) << 16);
    }
    u16* dst = hT + ((size_t)b * DOUT + d) * NN + n0 + half * 16;
    ((uint4*)dst)[0] = make_uint4(uu[0], uu[1], uu[2], uu[3]);
    ((uint4*)dst)[1] = make_uint4(uu[4], uu[5], uu[6], uu[7]);
  }
  // Wh1/Wh2 partials: thread = (r 0..31, g8 0..7), 16 d each
  {
    const int r = tid & 31, g8 = tid >> 5;
    float p1 = 0.f, p2 = 0.f;
#pragma unroll
    for (int q = 0; q < 16; ++q) {
      int d = g8 * 16 + q;
      float hv = T[d * 33 + r];
      p1 = fmaf(hv, a[d], p1);
      p2 = fmaf(hv, a[DOUT + d], p2);
    }
    P2a[g8 * 32 + r] = p1;
    P2b[g8 * 32 + r] = p2;
  }
  __syncthreads();
  if (tid < 32) {
    float s1 = 0.f, s2 = 0.f;
#pragma unroll
    for (int g8 = 0; g8 < 8; ++g8) { s1 += P2a[g8 * 32 + tid]; s2 += P2b[g8 * 32 + tid]; }
    Wh1[b * NN + n0 + tid] = s1;
    Wh2[b * NN + n0 + tid] = s2;
  }
}

// ---------------- k2a: adj -> bitmask (pure streaming) ----------------
// Thread packs 32 consecutive cols of one row: 8 independent int4 loads -> uint32.
// Block 256 = 2 rows (128 threads/row). Grid = BB*NN/2 = 8192 blocks.
// Bit layout: word j>>5, bit j&31 (LE) == byte j>>3, bit j&7 — same as k3 expects.
__global__ __launch_bounds__(256) void k2a_mask(
    const int* __restrict__ adj, unsigned int* __restrict__ mask32)
{
  const int tid = threadIdx.x;
  const int row = blockIdx.x * 2 + (tid >> 7);     // global row in [0, BB*NN)
  const int w   = tid & 127;                       // 32-col word index
  const int4* src = (const int4*)(adj + (size_t)row * NN) + w * 8;

  int4 v[8];
#pragma unroll
  for (int k = 0; k < 8; ++k) v[k] = src[k];

  unsigned int m = 0;
#pragma unroll
  for (int k = 0; k < 8; ++k) {
    m |= (v[k].x > 0 ? 1u : 0u) << (4 * k);
    m |= (v[k].y > 0 ? 1u : 0u) << (4 * k + 1);
    m |= (v[k].z > 0 ? 1u : 0u) << (4 * k + 2);
    m |= (v[k].w > 0 ? 1u : 0u) << (4 * k + 3);
  }
  mask32[(size_t)row * 128 + w] = m;
}

// ---------------- k2b: column sums S_j from bitmask ----------------
// grid (16 jt, 16 ic, BB), block 256: thread = col j, 256 rows per chunk.
// Loads grouped 8-deep (no stores/ballots in loop), register accumulation,
// one atomicAdd per thread at the end.
__global__ __launch_bounds__(256, 2) void k2b_colsum(
    const unsigned int* __restrict__ mask32, const float* __restrict__ Wh1,
    const float* __restrict__ Wh2, float* __restrict__ S)
{
  const int b = blockIdx.z, jt = blockIdx.x, ic = blockIdx.y;
  const int tid = threadIdx.x;
  const int j = jt * 256 + tid;
  const int i0 = ic * 256;
  const int jbit = tid & 31;

  const float wh2 = Wh2[b * NN + j];
  const unsigned int* mp = mask32 + ((size_t)b * NN + i0) * 128 + jt * 8 + (tid >> 5);
  const float* w1p = Wh1 + b * NN + i0;

  float s = 0.f;
  for (int g = 0; g < 32; ++g) {
    unsigned int mw[8];
    float w1v[8];
#pragma unroll
    for (int k = 0; k < 8; ++k) {
      mw[k]  = mp[(size_t)(g * 8 + k) * 128];
      w1v[k] = w1p[g * 8 + k];               // block-uniform -> scalar load
    }
#pragma unroll
    for (int k = 0; k < 8; ++k) {
      float E = exp_gelu(w1v[k] + wh2);
      s += ((mw[k] >> jbit) & 1u) ? E : 0.f;
    }
  }
  atomicAdd(&S[b * NN + j], s);
}

__global__ __launch_bounds__(256) void k25_rcp(const float* __restrict__ S,
                                               float* __restrict__ Sinv)
{
  int id = blockIdx.x * 256 + threadIdx.x;
  Sinv[id] = 1.0f / S[id];     // all-masked column cannot occur (p=0.5, N=4096)
}

// ---------------- k3: out_pre = P @ h via fp16 MFMA, P split hi+lo ----------------
// grid (NN/32, BB), block 256 = 4 waves: wave = (strip s in {0,1}, khalf h in {0,1}).
// Strip = 16 rows; A-frag (P) generated in-register; B (hT fp16) staged in LDS.
__global__ __launch_bounds__(256, 2) void k3_attn(
    const unsigned char* __restrict__ maskb, const float* __restrict__ Wh1,
    const float* __restrict__ Wh2, const float* __restrict__ Sinv,
    const u16* __restrict__ hT, float* __restrict__ out_pre)
{
  __shared__ __align__(16) u16 tile[2][128][72];   // [khalf][d][64 k + 8 pad] = 36.9 KB

  const int b = blockIdx.y;
  const int tid = threadIdx.x;
  const int wv = tid >> 6, lane = tid & 63;
  const int s = wv & 1, h = wv >> 1;
  const int i_base = blockIdx.x * 32 + s * 16;
  const int m = lane & 15, quad = lane >> 4;
  const int i = i_base + m;

  const float w1 = Wh1[b * NN + i];
  const unsigned char* mrow = maskb + ((size_t)b * NN + i) * 512;
  const u16* hTb = hT + (size_t)b * DOUT * NN;

  f32x4 acc[8];
#pragma unroll
  for (int t = 0; t < 8; ++t) acc[t] = (f32x4){0.f, 0.f, 0.f, 0.f};

  const int sd = tid & 127, ch = tid >> 7;
  const u16* src0 = hTb + (size_t)sd * NN + ch * 2048;

  for (int c = 0; c < 32; ++c) {
    __syncthreads();
    {
      const u16* src = src0 + c * 64;
#pragma unroll
      for (int g = 0; g < 8; ++g)
        *(uint4*)&tile[ch][sd][g * 8] = *(const uint4*)(src + g * 8);
    }
    __syncthreads();
#pragma unroll
    for (int ks = 0; ks < 2; ++ks) {
      const int j0 = h * 2048 + c * 64 + ks * 32;
      const int jq = j0 + quad * 8;
      const float4* wp = (const float4*)(Wh2 + b * NN + jq);
      float4 w2a = wp[0], w2b = wp[1];
      const float4* sp = (const float4*)(Sinv + b * NN + jq);
      float4 sva = sp[0], svb = sp[1];
      unsigned int mb = mrow[(j0 >> 3) + quad];

      float p0 = (mb & 1u)   ? exp_gelu(w1 + w2a.x) * sva.x : 0.f;
      float p1 = (mb & 2u)   ? exp_gelu(w1 + w2a.y) * sva.y : 0.f;
      float p2 = (mb & 4u)   ? exp_gelu(w1 + w2a.z) * sva.z : 0.f;
      float p3 = (mb & 8u)   ? exp_gelu(w1 + w2a.w) * sva.w : 0.f;
      float p4 = (mb & 16u)  ? exp_gelu(w1 + w2b.x) * svb.x : 0.f;
      float p5 = (mb & 32u)  ? exp_gelu(w1 + w2b.y) * svb.y : 0.f;
      float p6 = (mb & 64u)  ? exp_gelu(w1 + w2b.z) * svb.z : 0.f;
      float p7 = (mb & 128u) ? exp_gelu(w1 + w2b.w) * svb.w : 0.f;

      // fp16 hi + lo split of P: residual quantization ~2^-22
      f16x8 ah, al;
      float q[8] = {p0, p1, p2, p3, p4, p5, p6, p7};
#pragma unroll
      for (int e = 0; e < 8; ++e) {
        _Float16 hi = (_Float16)q[e];
        ah[e] = hi;
        al[e] = (_Float16)(q[e] - (float)hi);
      }

#pragma unroll
      for (int t = 0; t < 8; ++t) {
        f16x8 bf = *(const f16x8*)&tile[h][t * 16 + m][ks * 32 + quad * 8];
        acc[t] = __builtin_amdgcn_mfma_f32_16x16x32_f16(ah, bf, acc[t], 0, 0, 0);
        acc[t] = __builtin_amdgcn_mfma_f32_16x16x32_f16(al, bf, acc[t], 0, 0, 0);
      }
    }
  }

  // reduce the two K-halves per strip, then store (C layout: row=quad*4+reg, col=lane&15)
  __syncthreads();
  float* red = (float*)&tile[0][0][0];   // 16 KB needed, 36.9 KB available
  if (h == 1) {
#pragma unroll
    for (int t = 0; t < 8; ++t)
#pragma unroll
      for (int r = 0; r < 4; ++r)
        red[(t * 4 + r) * 128 + s * 64 + lane] = acc[t][r];
  }
  __syncthreads();
  if (h == 0) {
#pragma unroll
    for (int t = 0; t < 8; ++t) {
#pragma unroll
      for (int r = 0; r < 4; ++r) {
        float v = acc[t][r] + red[(t * 4 + r) * 128 + s * 64 + lane];
        out_pre[((size_t)b * NN + i_base + quad * 4 + r) * DOUT + t * 16 + m] = v;
      }
    }
  }
}

// ---------------- k4a: gelu + column sum-of-squares ----------------
__global__ __launch_bounds__(256) void k4a_gelu_norm(
    const float* __restrict__ out_pre, float* __restrict__ gout,
    float* __restrict__ norm2)
{
  __shared__ float pbuf[256];
  const int b = blockIdx.y;
  const int i0 = blockIdx.x * 64;
  const int tid = threadIdx.x;
  const int d = tid & 127, rh = tid >> 7;
  float acc = 0.f;
  for (int ii = rh; ii < 64; ii += 2) {
    size_t idx = ((size_t)b * NN + i0 + ii) * DOUT + d;
    float g = gelu_f(out_pre[idx]);
    gout[idx] = g;
    acc = fmaf(g, g, acc);
  }
  pbuf[tid] = acc;
  __syncthreads();
  if (tid < 128) atomicAdd(&norm2[b * DOUT + tid], pbuf[tid] + pbuf[tid + 128]);
}

// ---------------- k4b: scale by 1/max(||col||,1e-12) + bias ----------------
__global__ __launch_bounds__(256) void k4b_scale(
    float* __restrict__ out, const float* __restrict__ norm2,
    const float* __restrict__ bias)
{
  int id = blockIdx.x * 256 + threadIdx.x;
  int d = id & 127;
  int b = id >> 19;                        // N*DOUT = 2^19 per batch
  float nrm = sqrtf(norm2[b * DOUT + d]);
  float sc = 1.0f / fmaxf(nrm, 1e-12f);
  out[id] = fmaf(out[id], sc, bias[d]);
}

extern "C" void kernel_launch(void* const* d_in, const int* in_sizes, int n_in,
                              void* d_out, int out_size, void* d_ws, size_t ws_size,
                              hipStream_t stream)
{
  const float* x      = (const float*)d_in[0];
  const int*   adj    = (const int*)d_in[1];
  const float* weight = (const float*)d_in[2];
  const float* a      = (const float*)d_in[3];
  const float* bias   = (const float*)d_in[4];
  float* out = (float*)d_out;

  // workspace layout (all 16B aligned), ~21.3 MB total
  char* ws = (char*)d_ws;
  u16*   hT     = (u16*)ws;                                    // 4 MB
  float* Wh1    = (float*)(ws + (size_t)4 * 1024 * 1024);      // 64 KB
  float* Wh2    = Wh1 + BB * NN;                               // 64 KB
  float* S      = Wh2 + BB * NN;                               // 64 KB
  float* Sinv   = S + BB * NN;                                 // 64 KB
  unsigned int* mask32 = (unsigned int*)(Sinv + BB * NN);      // 8 MB
  float* out_pre = (float*)((char*)mask32 + (size_t)BB * NN * 512); // 8 MB
  float* norm2   = out_pre + (size_t)BB * NN * DOUT;           // 2 KB

  hipMemsetAsync(S, 0, (size_t)BB * NN * sizeof(float), stream);
  hipMemsetAsync(norm2, 0, (size_t)BB * DOUT * sizeof(float), stream);

  k1_proj<<<dim3(NN / 32, BB), 256, 0, stream>>>(x, weight, a, hT, Wh1, Wh2);
  k2a_mask<<<dim3(BB * NN / 2), 256, 0, stream>>>(adj, mask32);
  k2b_colsum<<<dim3(16, 16, BB), 256, 0, stream>>>(mask32, Wh1, Wh2, S);
  k25_rcp<<<dim3(BB * NN / 256), 256, 0, stream>>>(S, Sinv);
  k3_attn<<<dim3(NN / 32, BB), 256, 0, stream>>>((const unsigned char*)mask32,
                                                 Wh1, Wh2, Sinv, hT, out_pre);
  k4a_gelu_norm<<<dim3(64, BB), 256, 0, stream>>>(out_pre, out, norm2);
  k4b_scale<<<dim3((BB * NN * DOUT) / 256), 256, 0, stream>>>(out, norm2, bias);
}

// Round 5
// 568.251 us; speedup vs baseline: 1.1943x; 1.1009x over previous
//
#include <hip/hip_runtime.h>
#include <hip/hip_bf16.h>
#include <stdint.h>

// GAT-style attention layer, B=4 N=4096 Din=256 Dout=128, fp32 in/out.
// Pipeline:
//  k1 : h = x@W (fp32), store hT (fp16, [b][d][n]) + Wh1/Wh2 = h@a (fp32)
//  k2a: adj -> bitmask (pure stream, 268 MB read once)
//  k2b: per-column S_j = sum_i mask*exp(gelu(Wh1_i+Wh2_j)) from bitmask (VALU-bound)
//  k25: Sinv = 1/S
//  k3 : out_pre[i,d] = sum_j P(i,j) h[j,d]; barrier-free per-wave K-split,
//       coalesced global_load_lds staging, P in-register fp16 hi+lo
//  k4a: gelu + column sum-of-squares; k4b: L2-normalize over i + bias

#define NN   4096
#define BB   4
#define DIN  256
#define DOUT 128

typedef unsigned short u16;
typedef _Float16 f16x8 __attribute__((ext_vector_type(8)));
typedef __attribute__((ext_vector_type(4))) float f32x4;

__device__ __forceinline__ u16 f2h_bits(float f) {
  _Float16 h = (_Float16)f;          // v_cvt_f16_f32, RNE
  union { _Float16 h; u16 u; } v; v.h = h;
  return v.u;
}

// Abramowitz-Stegun 7.1.26, |err| < 1.5e-7
__device__ __forceinline__ float erf_f(float x) {
  float ax = __builtin_fabsf(x);
  float t  = __builtin_amdgcn_rcpf(__builtin_fmaf(0.3275911f, ax, 1.0f));
  float p  = __builtin_fmaf(1.061405429f, t, -1.453152027f);
  p = __builtin_fmaf(p, t, 1.421413741f);
  p = __builtin_fmaf(p, t, -0.284496736f);
  p = __builtin_fmaf(p, t, 0.254829592f);
  p = p * t;
  float e  = __expf(-ax * ax);
  float er = __builtin_fmaf(-p, e, 1.0f);
  return copysignf(er, x);
}

__device__ __forceinline__ float gelu_f(float z) {
  float hz = 0.5f * z;
  return __builtin_fmaf(hz, erf_f(z * 0.70710678118654752f), hz);
}

__device__ __forceinline__ float exp_gelu(float z) { return __expf(gelu_f(z)); }

// ---------------- k1: h = x@W, Wh1/Wh2, hT(fp16) ----------------
// grid (NN/32, BB), block 256.  32 rows/block; thread = (dgrp 0..31, rgrp 0..7),
// 4 d x 4 rows register tile.
__global__ __launch_bounds__(256, 2) void k1_proj(
    const float* __restrict__ x, const float* __restrict__ weight,
    const float* __restrict__ a, u16* __restrict__ hT,
    float* __restrict__ Wh1, float* __restrict__ Wh2)
{
  __shared__ float xs[32 * 256];     // 32 KB
  __shared__ float T[128 * 33];      // padded transpose buffer (16.9 KB)
  __shared__ float P2a[8 * 32], P2b[8 * 32];

  const int b = blockIdx.y, n0 = blockIdx.x * 32;
  const int tid = threadIdx.x;

  // stage x tile (32 rows x 256)
  const float4* xsrc = (const float4*)(x + ((size_t)b * NN + n0) * DIN);
  float4* xd = (float4*)xs;
#pragma unroll
  for (int v = 0; v < 8; ++v) xd[tid + v * 256] = xsrc[tid + v * 256];
  __syncthreads();

  const int dg = tid & 31, rg = tid >> 5;
  float acc[4][4] = {};
  const float4* W4 = (const float4*)weight;
#pragma unroll 4
  for (int k = 0; k < 256; ++k) {
    float4 wr = W4[k * 32 + dg];
#pragma unroll
    for (int rr = 0; rr < 4; ++rr) {
      float xv = xs[(rg * 4 + rr) * 256 + k];
      acc[rr][0] = fmaf(xv, wr.x, acc[rr][0]);
      acc[rr][1] = fmaf(xv, wr.y, acc[rr][1]);
      acc[rr][2] = fmaf(xv, wr.z, acc[rr][2]);
      acc[rr][3] = fmaf(xv, wr.w, acc[rr][3]);
    }
  }
  // transpose h into T[d][r]
#pragma unroll
  for (int rr = 0; rr < 4; ++rr)
#pragma unroll
    for (int dd = 0; dd < 4; ++dd)
      T[(dg * 4 + dd) * 33 + rg * 4 + rr] = acc[rr][dd];
  __syncthreads();

  // hT fp16 store: thread = (d 0..127, half 0..1), 16 values each
  {
    const int d = tid & 127, half = tid >> 7;
    unsigned int uu[8];
#pragma unroll
    for (int p = 0; p < 8; ++p) {
      float f0 = T[d * 33 + half * 16 + p * 2];
      float f1 = T[d * 33 + half * 16 + p * 2 + 1];
      uu[p] = (unsigned int)f2h_bits(f0) | ((unsigned int)f2h_bits(f1) << 16);
    }
    u16* dst = hT + ((size_t)b * DOUT + d) * NN + n0 + half * 16;
    ((uint4*)dst)[0] = make_uint4(uu[0], uu[1], uu[2], uu[3]);
    ((uint4*)dst)[1] = make_uint4(uu[4], uu[5], uu[6], uu[7]);
  }
  // Wh1/Wh2 partials: thread = (r 0..31, g8 0..7), 16 d each
  {
    const int r = tid & 31, g8 = tid >> 5;
    float p1 = 0.f, p2 = 0.f;
#pragma unroll
    for (int q = 0; q < 16; ++q) {
      int d = g8 * 16 + q;
      float hv = T[d * 33 + r];
      p1 = fmaf(hv, a[d], p1);
      p2 = fmaf(hv, a[DOUT + d], p2);
    }
    P2a[g8 * 32 + r] = p1;
    P2b[g8 * 32 + r] = p2;
  }
  __syncthreads();
  if (tid < 32) {
    float s1 = 0.f, s2 = 0.f;
#pragma unroll
    for (int g8 = 0; g8 < 8; ++g8) { s1 += P2a[g8 * 32 + tid]; s2 += P2b[g8 * 32 + tid]; }
    Wh1[b * NN + n0 + tid] = s1;
    Wh2[b * NN + n0 + tid] = s2;
  }
}

// ---------------- k2a: adj -> bitmask (pure streaming) ----------------
// Thread packs 32 consecutive cols of one row: 8 independent int4 loads -> uint32.
// Block 256 = 2 rows (128 threads/row). Grid = BB*NN/2 = 8192 blocks.
// Bit layout: word j>>5, bit j&31 (LE) == byte j>>3, bit j&7 — same as k3 expects.
__global__ __launch_bounds__(256) void k2a_mask(
    const int* __restrict__ adj, unsigned int* __restrict__ mask32)
{
  const int tid = threadIdx.x;
  const int row = blockIdx.x * 2 + (tid >> 7);     // global row in [0, BB*NN)
  const int w   = tid & 127;                       // 32-col word index
  const int4* src = (const int4*)(adj + (size_t)row * NN) + w * 8;

  int4 v[8];
#pragma unroll
  for (int k = 0; k < 8; ++k) v[k] = src[k];

  unsigned int m = 0;
#pragma unroll
  for (int k = 0; k < 8; ++k) {
    m |= (v[k].x > 0 ? 1u : 0u) << (4 * k);
    m |= (v[k].y > 0 ? 1u : 0u) << (4 * k + 1);
    m |= (v[k].z > 0 ? 1u : 0u) << (4 * k + 2);
    m |= (v[k].w > 0 ? 1u : 0u) << (4 * k + 3);
  }
  mask32[(size_t)row * 128 + w] = m;
}

// ---------------- k2b: column sums S_j from bitmask ----------------
// grid (16 jt, 16 ic, BB), block 256: thread = col j, 256 rows per chunk.
// Loads grouped 8-deep (no stores/ballots in loop), register accumulation,
// one atomicAdd per thread at the end.
__global__ __launch_bounds__(256, 2) void k2b_colsum(
    const unsigned int* __restrict__ mask32, const float* __restrict__ Wh1,
    const float* __restrict__ Wh2, float* __restrict__ S)
{
  const int b = blockIdx.z, jt = blockIdx.x, ic = blockIdx.y;
  const int tid = threadIdx.x;
  const int j = jt * 256 + tid;
  const int i0 = ic * 256;
  const int jbit = tid & 31;

  const float wh2 = Wh2[b * NN + j];
  const unsigned int* mp = mask32 + ((size_t)b * NN + i0) * 128 + jt * 8 + (tid >> 5);
  const float* w1p = Wh1 + b * NN + i0;

  float s = 0.f;
  for (int g = 0; g < 32; ++g) {
    unsigned int mw[8];
    float w1v[8];
#pragma unroll
    for (int k = 0; k < 8; ++k) {
      mw[k]  = mp[(size_t)(g * 8 + k) * 128];
      w1v[k] = w1p[g * 8 + k];               // block-uniform -> scalar load
    }
#pragma unroll
    for (int k = 0; k < 8; ++k) {
      float E = exp_gelu(w1v[k] + wh2);
      s += ((mw[k] >> jbit) & 1u) ? E : 0.f;
    }
  }
  atomicAdd(&S[b * NN + j], s);
}

__global__ __launch_bounds__(256) void k25_rcp(const float* __restrict__ S,
                                               float* __restrict__ Sinv)
{
  int id = blockIdx.x * 256 + threadIdx.x;
  Sinv[id] = 1.0f / S[id];     // all-masked column cannot occur (p=0.5, N=4096)
}

// ---------------- k3: out_pre = P @ h via fp16 MFMA, barrier-free ----------------
// grid (NN/16, BB) = 1024 blocks, block 256 = 4 waves. Block covers 16 rows.
// Wave w owns j in [w*1024, (w+1)*1024) and a private 8 KB LDS buffer:
// no __syncthreads in the K-loop (waitcnt-only ordering within the wave).
// Staging: coalesced global_load_lds width=16 (lane l -> LDS base + l*16 B).
// One DMA inst = 64 lanes x 16 B = 1024 B = 512 u16  -> inst stride 512 u16.
// K-split partials reduced across the 4 waves at the end (2 barriers total).
__global__ __launch_bounds__(256, 4) void k3_attn(
    const unsigned int* __restrict__ mask32, const float* __restrict__ Wh1,
    const float* __restrict__ Wh2, const float* __restrict__ Sinv,
    const u16* __restrict__ hT, float* __restrict__ out_pre)
{
  __shared__ __align__(16) u16 buf[4][128 * 32];   // 4 waves x 8 KB = 32 KB

  const int b = blockIdx.y;
  const int i0 = blockIdx.x * 16;
  const int tid = threadIdx.x;
  const int w = tid >> 6, lane = tid & 63;
  const int m = lane & 15, quad = lane >> 4;
  const int i = i0 + m;

  const float w1 = Wh1[b * NN + i];
  const unsigned int* mrow = mask32 + ((size_t)b * NN + i) * 128;
  const u16* hTb = hT + (size_t)b * DOUT * NN;

  // staging: lane l covers row (l>>2)+inst*16, j-offset (l&3)*8 -> LDS u16 ofs l*8
  const u16* srcbase = hTb + (size_t)(lane >> 2) * NN + (lane & 3) * 8;

  f32x4 acc[8];
#pragma unroll
  for (int t = 0; t < 8; ++t) acc[t] = (f32x4){0.f, 0.f, 0.f, 0.f};

  for (int c = 0; c < 32; ++c) {
    const int j0 = w * 1024 + c * 32;

    // WAR: previous chunk's ds_reads must complete before DMA overwrites LDS
    __builtin_amdgcn_s_waitcnt(0xC07F);   // lgkmcnt(0) only
#pragma unroll
    for (int inst = 0; inst < 8; ++inst) {
      const u16* g = srcbase + (size_t)inst * 16 * NN + j0;
      __builtin_amdgcn_global_load_lds(
          (const __attribute__((address_space(1))) void*)g,
          (__attribute__((address_space(3))) void*)&buf[w][inst * 512],
          16, 0, 0);
    }

    // per-lane P for j = j0 + quad*8 .. +8
    const unsigned int mb = (mrow[j0 >> 5] >> (quad * 8)) & 0xFFu;
    const int jq = j0 + quad * 8;
    const float4* wp = (const float4*)(Wh2 + b * NN + jq);
    float4 w2a = wp[0], w2b = wp[1];
    const float4* sp = (const float4*)(Sinv + b * NN + jq);
    float4 sva = sp[0], svb = sp[1];

    float q[8];
    q[0] = (mb & 1u)   ? exp_gelu(w1 + w2a.x) * sva.x : 0.f;
    q[1] = (mb & 2u)   ? exp_gelu(w1 + w2a.y) * sva.y : 0.f;
    q[2] = (mb & 4u)   ? exp_gelu(w1 + w2a.z) * sva.z : 0.f;
    q[3] = (mb & 8u)   ? exp_gelu(w1 + w2a.w) * sva.w : 0.f;
    q[4] = (mb & 16u)  ? exp_gelu(w1 + w2b.x) * svb.x : 0.f;
    q[5] = (mb & 32u)  ? exp_gelu(w1 + w2b.y) * svb.y : 0.f;
    q[6] = (mb & 64u)  ? exp_gelu(w1 + w2b.z) * svb.z : 0.f;
    q[7] = (mb & 128u) ? exp_gelu(w1 + w2b.w) * svb.w : 0.f;

    // fp16 hi + lo split of P: residual quantization ~2^-22
    f16x8 ah, al;
#pragma unroll
    for (int e = 0; e < 8; ++e) {
      _Float16 hi = (_Float16)q[e];
      ah[e] = hi;
      al[e] = (_Float16)(q[e] - (float)hi);
    }

    // drain the DMA before reading LDS
    __builtin_amdgcn_s_waitcnt(0x0F70);   // vmcnt(0) only

#pragma unroll
    for (int t = 0; t < 8; ++t) {
      f16x8 bf = *(const f16x8*)&buf[w][(t * 16 + m) * 32 + quad * 8];
      acc[t] = __builtin_amdgcn_mfma_f32_16x16x32_f16(ah, bf, acc[t], 0, 0, 0);
      acc[t] = __builtin_amdgcn_mfma_f32_16x16x32_f16(al, bf, acc[t], 0, 0, 0);
    }
  }

  // K-split reduce across the 4 waves (reuse buf as 32 KB fp32 scratch)
  __syncthreads();
  float* red = (float*)&buf[0][0];
#pragma unroll
  for (int t = 0; t < 8; ++t)
#pragma unroll
    for (int r = 0; r < 4; ++r)
      red[w * 2048 + (t * 4 + r) * 64 + lane] = acc[t][r];
  __syncthreads();
  // wave w finalizes d-tiles t = 2w, 2w+1 (C layout: row=quad*4+r, col=t*16+m)
#pragma unroll
  for (int tt = 0; tt < 2; ++tt) {
    const int t = w * 2 + tt;
#pragma unroll
    for (int r = 0; r < 4; ++r) {
      const int o = (t * 4 + r) * 64 + lane;
      float v = red[o] + red[2048 + o] + red[4096 + o] + red[6144 + o];
      out_pre[((size_t)b * NN + i0 + quad * 4 + r) * DOUT + t * 16 + m] = v;
    }
  }
}

// ---------------- k4a: gelu + column sum-of-squares ----------------
__global__ __launch_bounds__(256) void k4a_gelu_norm(
    const float* __restrict__ out_pre, float* __restrict__ gout,
    float* __restrict__ norm2)
{
  __shared__ float pbuf[256];
  const int b = blockIdx.y;
  const int i0 = blockIdx.x * 64;
  const int tid = threadIdx.x;
  const int d = tid & 127, rh = tid >> 7;
  float acc = 0.f;
  for (int ii = rh; ii < 64; ii += 2) {
    size_t idx = ((size_t)b * NN + i0 + ii) * DOUT + d;
    float g = gelu_f(out_pre[idx]);
    gout[idx] = g;
    acc = fmaf(g, g, acc);
  }
  pbuf[tid] = acc;
  __syncthreads();
  if (tid < 128) atomicAdd(&norm2[b * DOUT + tid], pbuf[tid] + pbuf[tid + 128]);
}

// ---------------- k4b: scale by 1/max(||col||,1e-12) + bias ----------------
__global__ __launch_bounds__(256) void k4b_scale(
    float* __restrict__ out, const float* __restrict__ norm2,
    const float* __restrict__ bias)
{
  int id = blockIdx.x * 256 + threadIdx.x;
  int d = id & 127;
  int b = id >> 19;                        // N*DOUT = 2^19 per batch
  float nrm = sqrtf(norm2[b * DOUT + d]);
  float sc = 1.0f / fmaxf(nrm, 1e-12f);
  out[id] = fmaf(out[id], sc, bias[d]);
}

extern "C" void kernel_launch(void* const* d_in, const int* in_sizes, int n_in,
                              void* d_out, int out_size, void* d_ws, size_t ws_size,
                              hipStream_t stream)
{
  const float* x      = (const float*)d_in[0];
  const int*   adj    = (const int*)d_in[1];
  const float* weight = (const float*)d_in[2];
  const float* a      = (const float*)d_in[3];
  const float* bias   = (const float*)d_in[4];
  float* out = (float*)d_out;

  // workspace layout (all 16B aligned), ~21.3 MB total
  char* ws = (char*)d_ws;
  u16*   hT     = (u16*)ws;                                    // 4 MB
  float* Wh1    = (float*)(ws + (size_t)4 * 1024 * 1024);      // 64 KB
  float* Wh2    = Wh1 + BB * NN;                               // 64 KB
  float* S      = Wh2 + BB * NN;                               // 64 KB
  float* Sinv   = S + BB * NN;                                 // 64 KB
  unsigned int* mask32 = (unsigned int*)(Sinv + BB * NN);      // 8 MB
  float* out_pre = (float*)((char*)mask32 + (size_t)BB * NN * 512); // 8 MB
  float* norm2   = out_pre + (size_t)BB * NN * DOUT;           // 2 KB

  hipMemsetAsync(S, 0, (size_t)BB * NN * sizeof(float), stream);
  hipMemsetAsync(norm2, 0, (size_t)BB * DOUT * sizeof(float), stream);

  k1_proj<<<dim3(NN / 32, BB), 256, 0, stream>>>(x, weight, a, hT, Wh1, Wh2);
  k2a_mask<<<dim3(BB * NN / 2), 256, 0, stream>>>(adj, mask32);
  k2b_colsum<<<dim3(16, 16, BB), 256, 0, stream>>>(mask32, Wh1, Wh2, S);
  k25_rcp<<<dim3(BB * NN / 256), 256, 0, stream>>>(S, Sinv);
  k3_attn<<<dim3(NN / 16, BB), 256, 0, stream>>>(mask32, Wh1, Wh2, Sinv, hT, out_pre);
  k4a_gelu_norm<<<dim3(64, BB), 256, 0, stream>>>(out_pre, out, norm2);
  k4b_scale<<<dim3((BB * NN * DOUT) / 256), 256, 0, stream>>>(out, norm2, bias);
}

// Round 6
// 515.610 us; speedup vs baseline: 1.3162x; 1.1021x over previous
//
#include <hip/hip_runtime.h>
#include <hip/hip_bf16.h>
#include <stdint.h>

// GAT-style attention layer, B=4 N=4096 Din=256 Dout=128, fp32 in/out.
// Pipeline:
//  k1 : h = x@W (fp32), store hT (fp16, [b][d][n]) + Wh1/Wh2 = h@a (fp32)
//  k2 : ONE coalesced pass over adj: S_j (atomicAdd) + transposed bitmask
//       m32[b][jw][i] (jw = j>>5), all loads/stores coalesced
//  k25: Sinv = 1/S
//  k3 : out_pre[i,d] = sum_j P(i,j) h[j,d]; 32 rows/wave (2 row-tiles per
//       staged B-tile -> half the L2 traffic), barrier-free K-loop,
//       coalesced global_load_lds staging, P in-register fp16 hi+lo
//  k4a: gelu + column sum-of-squares; k4b: L2-normalize over i + bias

#define NN   4096
#define BB   4
#define DIN  256
#define DOUT 128

typedef unsigned short u16;
typedef _Float16 f16x8 __attribute__((ext_vector_type(8)));
typedef __attribute__((ext_vector_type(4))) float f32x4;

__device__ __forceinline__ u16 f2h_bits(float f) {
  _Float16 h = (_Float16)f;          // v_cvt_f16_f32, RNE
  union { _Float16 h; u16 u; } v; v.h = h;
  return v.u;
}

// Abramowitz-Stegun 7.1.26, |err| < 1.5e-7
__device__ __forceinline__ float erf_f(float x) {
  float ax = __builtin_fabsf(x);
  float t  = __builtin_amdgcn_rcpf(__builtin_fmaf(0.3275911f, ax, 1.0f));
  float p  = __builtin_fmaf(1.061405429f, t, -1.453152027f);
  p = __builtin_fmaf(p, t, 1.421413741f);
  p = __builtin_fmaf(p, t, -0.284496736f);
  p = __builtin_fmaf(p, t, 0.254829592f);
  p = p * t;
  float e  = __expf(-ax * ax);
  float er = __builtin_fmaf(-p, e, 1.0f);
  return copysignf(er, x);
}

__device__ __forceinline__ float gelu_f(float z) {
  float hz = 0.5f * z;
  return __builtin_fmaf(hz, erf_f(z * 0.70710678118654752f), hz);
}

__device__ __forceinline__ float exp_gelu(float z) { return __expf(gelu_f(z)); }

// ---------------- k1: h = x@W, Wh1/Wh2, hT(fp16) ----------------
// grid (NN/32, BB), block 256.  32 rows/block; thread = (dgrp 0..31, rgrp 0..7),
// 4 d x 4 rows register tile.
__global__ __launch_bounds__(256, 2) void k1_proj(
    const float* __restrict__ x, const float* __restrict__ weight,
    const float* __restrict__ a, u16* __restrict__ hT,
    float* __restrict__ Wh1, float* __restrict__ Wh2)
{
  __shared__ float xs[32 * 256];     // 32 KB
  __shared__ float T[128 * 33];      // padded transpose buffer (16.9 KB)
  __shared__ float P2a[8 * 32], P2b[8 * 32];

  const int b = blockIdx.y, n0 = blockIdx.x * 32;
  const int tid = threadIdx.x;

  // stage x tile (32 rows x 256)
  const float4* xsrc = (const float4*)(x + ((size_t)b * NN + n0) * DIN);
  float4* xd = (float4*)xs;
#pragma unroll
  for (int v = 0; v < 8; ++v) xd[tid + v * 256] = xsrc[tid + v * 256];
  __syncthreads();

  const int dg = tid & 31, rg = tid >> 5;
  float acc[4][4] = {};
  const float4* W4 = (const float4*)weight;
#pragma unroll 4
  for (int k = 0; k < 256; ++k) {
    float4 wr = W4[k * 32 + dg];
#pragma unroll
    for (int rr = 0; rr < 4; ++rr) {
      float xv = xs[(rg * 4 + rr) * 256 + k];
      acc[rr][0] = fmaf(xv, wr.x, acc[rr][0]);
      acc[rr][1] = fmaf(xv, wr.y, acc[rr][1]);
      acc[rr][2] = fmaf(xv, wr.z, acc[rr][2]);
      acc[rr][3] = fmaf(xv, wr.w, acc[rr][3]);
    }
  }
  // transpose h into T[d][r]
#pragma unroll
  for (int rr = 0; rr < 4; ++rr)
#pragma unroll
    for (int dd = 0; dd < 4; ++dd)
      T[(dg * 4 + dd) * 33 + rg * 4 + rr] = acc[rr][dd];
  __syncthreads();

  // hT fp16 store: thread = (d 0..127, half 0..1), 16 values each
  {
    const int d = tid & 127, half = tid >> 7;
    unsigned int uu[8];
#pragma unroll
    for (int p = 0; p < 8; ++p) {
      float f0 = T[d * 33 + half * 16 + p * 2];
      float f1 = T[d * 33 + half * 16 + p * 2 + 1];
      uu[p] = (unsigned int)f2h_bits(f0) | ((unsigned int)f2h_bits(f1) << 16);
    }
    u16* dst = hT + ((size_t)b * DOUT + d) * NN + n0 + half * 16;
    ((uint4*)dst)[0] = make_uint4(uu[0], uu[1], uu[2], uu[3]);
    ((uint4*)dst)[1] = make_uint4(uu[4], uu[5], uu[6], uu[7]);
  }
  // Wh1/Wh2 partials: thread = (r 0..31, g8 0..7), 16 d each
  {
    const int r = tid & 31, g8 = tid >> 5;
    float p1 = 0.f, p2 = 0.f;
#pragma unroll
    for (int q = 0; q < 16; ++q) {
      int d = g8 * 16 + q;
      float hv = T[d * 33 + r];
      p1 = fmaf(hv, a[d], p1);
      p2 = fmaf(hv, a[DOUT + d], p2);
    }
    P2a[g8 * 32 + r] = p1;
    P2b[g8 * 32 + r] = p2;
  }
  __syncthreads();
  if (tid < 32) {
    float s1 = 0.f, s2 = 0.f;
#pragma unroll
    for (int g8 = 0; g8 < 8; ++g8) { s1 += P2a[g8 * 32 + tid]; s2 += P2b[g8 * 32 + tid]; }
    Wh1[b * NN + n0 + tid] = s1;
    Wh2[b * NN + n0 + tid] = s2;
  }
}

// ---------------- k2: fused adj pass -> S_j + transposed bitmask ----------------
// grid (16 jt, 8 ic, BB) = 512 blocks, block 256: thread = column j = jt*256+tid,
// 512 rows per thread. adj loads are lane-consecutive 4 B (perfectly coalesced).
// Per 64-row group: 64 ballots accumulated into per-lane u64 (lane ii keeps row
// i0+g*64+ii), then ONE coalesced store into transposed planes m32[b][jw][i].
__global__ __launch_bounds__(256, 2) void k2_fused(
    const int* __restrict__ adj, const float* __restrict__ Wh1,
    const float* __restrict__ Wh2, float* __restrict__ S,
    unsigned int* __restrict__ m32)
{
  const int b = blockIdx.z, jt = blockIdx.x, ic = blockIdx.y;
  const int tid = threadIdx.x;
  const int j = jt * 256 + tid;
  const int lane = tid & 63;
  const int jg = jt * 4 + (tid >> 6);      // global 64-j group
  const int i0 = ic * 512;

  const float wh2 = Wh2[b * NN + j];
  const int* ap = adj + ((size_t)b * NN + i0) * NN + j;
  const float* w1p = Wh1 + b * NN + i0;
  unsigned int* mlo = m32 + ((size_t)b * 128 + jg * 2) * NN + i0;
  unsigned int* mhi = mlo + NN;

  float s = 0.f;
  for (int g = 0; g < 8; ++g) {            // 8 groups of 64 rows
    unsigned long long acc64 = 0ull;
#pragma unroll
    for (int gg = 0; gg < 8; ++gg) {       // 8 sub-batches of 8 rows
      int av[8]; float w1v[8];
#pragma unroll
      for (int k = 0; k < 8; ++k) {
        const int ii = g * 64 + gg * 8 + k;
        av[k]  = ap[(size_t)ii * NN];
        w1v[k] = w1p[ii];                  // block-uniform -> scalar load
      }
#pragma unroll
      for (int k = 0; k < 8; ++k) {
        const unsigned long long bal = __ballot(av[k] > 0);
        if (lane == gg * 8 + k) acc64 = bal;   // cndmask keep
        const float E = exp_gelu(w1v[k] + wh2);
        s += (av[k] > 0) ? E : 0.f;
      }
    }
    mlo[g * 64 + lane] = (unsigned int)acc64;          // coalesced 256 B
    mhi[g * 64 + lane] = (unsigned int)(acc64 >> 32);  // coalesced 256 B
  }
  atomicAdd(&S[b * NN + j], s);
}

__global__ __launch_bounds__(256) void k25_rcp(const float* __restrict__ S,
                                               float* __restrict__ Sinv)
{
  int id = blockIdx.x * 256 + threadIdx.x;
  Sinv[id] = 1.0f / S[id];     // all-masked column cannot occur (p=0.5, N=4096)
}

// ---------------- k3: out_pre = P @ h via fp16 MFMA, 32 rows/wave ----------------
// grid (NN/32, BB) = 512 blocks, block 256 = 4 waves; block covers 32 rows.
// Wave w owns j-quarter [w*1024, +1024) and a private 8 KB LDS buffer; the
// staged B-tile feeds TWO A-row-tiles (rows i0+m and i0+16+m) -> L2 traffic
// halves vs 16 rows/wave. No __syncthreads in the K-loop.
// Staging: coalesced global_load_lds width=16 (lane l -> LDS base + l*16 B);
// one DMA inst = 64 lanes x 16 B = 512 u16 -> inst stride 512 u16.
// Mask read from transposed planes m32[b][jw][i] (coalesced over m).
__global__ __launch_bounds__(256, 2) void k3_attn(
    const unsigned int* __restrict__ m32, const float* __restrict__ Wh1,
    const float* __restrict__ Wh2, const float* __restrict__ Sinv,
    const u16* __restrict__ hT, float* __restrict__ out_pre)
{
  __shared__ __align__(16) u16 buf[4][128 * 32];   // 4 waves x 8 KB = 32 KB

  const int b = blockIdx.y;
  const int i0 = blockIdx.x * 32;
  const int tid = threadIdx.x;
  const int w = tid >> 6, lane = tid & 63;
  const int m = lane & 15, quad = lane >> 4;

  const float w1a = Wh1[b * NN + i0 + m];
  const float w1b = Wh1[b * NN + i0 + 16 + m];
  const unsigned int* mbase = m32 + (size_t)b * 128 * NN;
  const u16* hTb = hT + (size_t)b * DOUT * NN;
  // staging: lane l covers row (l>>2)+inst*16, j-offset (l&3)*8 -> LDS u16 ofs l*8
  const u16* srcbase = hTb + (size_t)(lane >> 2) * NN + (lane & 3) * 8;

  f32x4 acc0[8], acc1[8];
#pragma unroll
  for (int t = 0; t < 8; ++t) {
    acc0[t] = (f32x4){0.f, 0.f, 0.f, 0.f};
    acc1[t] = (f32x4){0.f, 0.f, 0.f, 0.f};
  }

  for (int c = 0; c < 32; ++c) {
    const int j0 = w * 1024 + c * 32;
    const int jw = j0 >> 5;

    // WAR: previous chunk's ds_reads must complete before DMA overwrites LDS
    __builtin_amdgcn_s_waitcnt(0xC07F);   // lgkmcnt(0) only
#pragma unroll
    for (int inst = 0; inst < 8; ++inst) {
      const u16* g = srcbase + (size_t)inst * 16 * NN + j0;
      __builtin_amdgcn_global_load_lds(
          (const __attribute__((address_space(1))) void*)g,
          (__attribute__((address_space(3))) void*)&buf[w][inst * 512],
          16, 0, 0);
    }

    // masks for both row-tiles (transposed planes, coalesced over m)
    const unsigned int Ma = mbase[(size_t)jw * NN + i0 + m];
    const unsigned int Mb = mbase[(size_t)jw * NN + i0 + 16 + m];
    const unsigned int mba = (Ma >> (quad * 8)) & 0xFFu;
    const unsigned int mbb = (Mb >> (quad * 8)) & 0xFFu;

    const int jq = j0 + quad * 8;
    const float4* wp = (const float4*)(Wh2 + b * NN + jq);
    float4 w2a = wp[0], w2b = wp[1];
    const float4* sp = (const float4*)(Sinv + b * NN + jq);
    float4 sva = sp[0], svb = sp[1];

    float q[8];
    f16x8 ah_a, al_a, ah_b, al_b;

    // row-tile a (rows i0..i0+15)
    q[0] = (mba & 1u)   ? exp_gelu(w1a + w2a.x) * sva.x : 0.f;
    q[1] = (mba & 2u)   ? exp_gelu(w1a + w2a.y) * sva.y : 0.f;
    q[2] = (mba & 4u)   ? exp_gelu(w1a + w2a.z) * sva.z : 0.f;
    q[3] = (mba & 8u)   ? exp_gelu(w1a + w2a.w) * sva.w : 0.f;
    q[4] = (mba & 16u)  ? exp_gelu(w1a + w2b.x) * svb.x : 0.f;
    q[5] = (mba & 32u)  ? exp_gelu(w1a + w2b.y) * svb.y : 0.f;
    q[6] = (mba & 64u)  ? exp_gelu(w1a + w2b.z) * svb.z : 0.f;
    q[7] = (mba & 128u) ? exp_gelu(w1a + w2b.w) * svb.w : 0.f;
#pragma unroll
    for (int e = 0; e < 8; ++e) {
      _Float16 hi = (_Float16)q[e];
      ah_a[e] = hi;
      al_a[e] = (_Float16)(q[e] - (float)hi);
    }
    // row-tile b (rows i0+16..i0+31)
    q[0] = (mbb & 1u)   ? exp_gelu(w1b + w2a.x) * sva.x : 0.f;
    q[1] = (mbb & 2u)   ? exp_gelu(w1b + w2a.y) * sva.y : 0.f;
    q[2] = (mbb & 4u)   ? exp_gelu(w1b + w2a.z) * sva.z : 0.f;
    q[3] = (mbb & 8u)   ? exp_gelu(w1b + w2a.w) * sva.w : 0.f;
    q[4] = (mbb & 16u)  ? exp_gelu(w1b + w2b.x) * svb.x : 0.f;
    q[5] = (mbb & 32u)  ? exp_gelu(w1b + w2b.y) * svb.y : 0.f;
    q[6] = (mbb & 64u)  ? exp_gelu(w1b + w2b.z) * svb.z : 0.f;
    q[7] = (mbb & 128u) ? exp_gelu(w1b + w2b.w) * svb.w : 0.f;
#pragma unroll
    for (int e = 0; e < 8; ++e) {
      _Float16 hi = (_Float16)q[e];
      ah_b[e] = hi;
      al_b[e] = (_Float16)(q[e] - (float)hi);
    }

    // drain the DMA before reading LDS
    __builtin_amdgcn_s_waitcnt(0x0F70);   // vmcnt(0) only

#pragma unroll
    for (int t = 0; t < 8; ++t) {
      f16x8 bf = *(const f16x8*)&buf[w][(t * 16 + m) * 32 + quad * 8];
      acc0[t] = __builtin_amdgcn_mfma_f32_16x16x32_f16(ah_a, bf, acc0[t], 0, 0, 0);
      acc0[t] = __builtin_amdgcn_mfma_f32_16x16x32_f16(al_a, bf, acc0[t], 0, 0, 0);
      acc1[t] = __builtin_amdgcn_mfma_f32_16x16x32_f16(ah_b, bf, acc1[t], 0, 0, 0);
      acc1[t] = __builtin_amdgcn_mfma_f32_16x16x32_f16(al_b, bf, acc1[t], 0, 0, 0);
    }
  }

  // K-split reduce across the 4 waves, two passes (row-tile 0 then 1).
  // red needs 4 waves x 2048 floats = 32 KB = exactly buf.
  float* red = (float*)&buf[0][0];
#pragma unroll
  for (int rt = 0; rt < 2; ++rt) {
    __syncthreads();
#pragma unroll
    for (int t = 0; t < 8; ++t)
#pragma unroll
      for (int r = 0; r < 4; ++r)
        red[w * 2048 + (t * 4 + r) * 64 + lane] = rt ? acc1[t][r] : acc0[t][r];
    __syncthreads();
    // wave w finalizes d-tiles t = 2w, 2w+1 (C layout: row=quad*4+r, col=t*16+m)
#pragma unroll
    for (int tt = 0; tt < 2; ++tt) {
      const int t = w * 2 + tt;
#pragma unroll
      for (int r = 0; r < 4; ++r) {
        const int o = (t * 4 + r) * 64 + lane;
        float v = red[o] + red[2048 + o] + red[4096 + o] + red[6144 + o];
        out_pre[((size_t)b * NN + i0 + rt * 16 + quad * 4 + r) * DOUT + t * 16 + m] = v;
      }
    }
  }
}

// ---------------- k4a: gelu + column sum-of-squares ----------------
__global__ __launch_bounds__(256) void k4a_gelu_norm(
    const float* __restrict__ out_pre, float* __restrict__ gout,
    float* __restrict__ norm2)
{
  __shared__ float pbuf[256];
  const int b = blockIdx.y;
  const int i0 = blockIdx.x * 64;
  const int tid = threadIdx.x;
  const int d = tid & 127, rh = tid >> 7;
  float acc = 0.f;
  for (int ii = rh; ii < 64; ii += 2) {
    size_t idx = ((size_t)b * NN + i0 + ii) * DOUT + d;
    float g = gelu_f(out_pre[idx]);
    gout[idx] = g;
    acc = fmaf(g, g, acc);
  }
  pbuf[tid] = acc;
  __syncthreads();
  if (tid < 128) atomicAdd(&norm2[b * DOUT + tid], pbuf[tid] + pbuf[tid + 128]);
}

// ---------------- k4b: scale by 1/max(||col||,1e-12) + bias ----------------
__global__ __launch_bounds__(256) void k4b_scale(
    float* __restrict__ out, const float* __restrict__ norm2,
    const float* __restrict__ bias)
{
  int id = blockIdx.x * 256 + threadIdx.x;
  int d = id & 127;
  int b = id >> 19;                        // N*DOUT = 2^19 per batch
  float nrm = sqrtf(norm2[b * DOUT + d]);
  float sc = 1.0f / fmaxf(nrm, 1e-12f);
  out[id] = fmaf(out[id], sc, bias[d]);
}

extern "C" void kernel_launch(void* const* d_in, const int* in_sizes, int n_in,
                              void* d_out, int out_size, void* d_ws, size_t ws_size,
                              hipStream_t stream)
{
  const float* x      = (const float*)d_in[0];
  const int*   adj    = (const int*)d_in[1];
  const float* weight = (const float*)d_in[2];
  const float* a      = (const float*)d_in[3];
  const float* bias   = (const float*)d_in[4];
  float* out = (float*)d_out;

  // workspace layout (all 16B aligned), ~21.3 MB total
  char* ws = (char*)d_ws;
  u16*   hT     = (u16*)ws;                                    // 4 MB
  float* Wh1    = (float*)(ws + (size_t)4 * 1024 * 1024);      // 64 KB
  float* Wh2    = Wh1 + BB * NN;                               // 64 KB
  float* S      = Wh2 + BB * NN;                               // 64 KB
  float* Sinv   = S + BB * NN;                                 // 64 KB
  unsigned int* m32 = (unsigned int*)(Sinv + BB * NN);         // 8 MB, [b][128][4096]
  float* out_pre = (float*)((char*)m32 + (size_t)BB * 128 * NN * 4); // 8 MB
  float* norm2   = out_pre + (size_t)BB * NN * DOUT;           // 2 KB

  hipMemsetAsync(S, 0, (size_t)BB * NN * sizeof(float), stream);
  hipMemsetAsync(norm2, 0, (size_t)BB * DOUT * sizeof(float), stream);

  k1_proj<<<dim3(NN / 32, BB), 256, 0, stream>>>(x, weight, a, hT, Wh1, Wh2);
  k2_fused<<<dim3(16, 8, BB), 256, 0, stream>>>(adj, Wh1, Wh2, S, m32);
  k25_rcp<<<dim3(BB * NN / 256), 256, 0, stream>>>(S, Sinv);
  k3_attn<<<dim3(NN / 32, BB), 256, 0, stream>>>(m32, Wh1, Wh2, Sinv, hT, out_pre);
  k4a_gelu_norm<<<dim3(64, BB), 256, 0, stream>>>(out_pre, out, norm2);
  k4b_scale<<<dim3((BB * NN * DOUT) / 256), 256, 0, stream>>>(out, norm2, bias);
}

// Round 7
// 509.964 us; speedup vs baseline: 1.3308x; 1.0111x over previous
//
#include <hip/hip_runtime.h>
#include <hip/hip_bf16.h>
#include <stdint.h>

// GAT-style attention layer, B=4 N=4096 Din=256 Dout=128, fp32 in/out.
// Pipeline:
//  k1 : h = x@W (fp32), store hT (fp16, [b][d][n]) + Wh1/Wh2 = h@a (fp32)
//  k2 : ONE coalesced pass over adj: S_j (atomicAdd) + transposed bitmask
//       m32[b][jw][i]; 2048 blocks (8/CU) for full HBM MLP
//  k25: Sinv = 1/S
//  k3 : out_pre = P @ h, fp16 MFMA; 512-thr blocks, 8-way K-split (wave owns
//       512 j), 32 rows/block -> 512 MB L2 traffic AND 4 waves/SIMD
//  k4a: gelu + column sum-of-squares; k4b: L2-normalize over i + bias

#define NN   4096
#define BB   4
#define DIN  256
#define DOUT 128

typedef unsigned short u16;
typedef _Float16 f16x8 __attribute__((ext_vector_type(8)));
typedef __attribute__((ext_vector_type(4))) float f32x4;

__device__ __forceinline__ u16 f2h_bits(float f) {
  _Float16 h = (_Float16)f;          // v_cvt_f16_f32, RNE
  union { _Float16 h; u16 u; } v; v.h = h;
  return v.u;
}

// Abramowitz-Stegun 7.1.26, |err| < 1.5e-7
__device__ __forceinline__ float erf_f(float x) {
  float ax = __builtin_fabsf(x);
  float t  = __builtin_amdgcn_rcpf(__builtin_fmaf(0.3275911f, ax, 1.0f));
  float p  = __builtin_fmaf(1.061405429f, t, -1.453152027f);
  p = __builtin_fmaf(p, t, 1.421413741f);
  p = __builtin_fmaf(p, t, -0.284496736f);
  p = __builtin_fmaf(p, t, 0.254829592f);
  p = p * t;
  float e  = __expf(-ax * ax);
  float er = __builtin_fmaf(-p, e, 1.0f);
  return copysignf(er, x);
}

__device__ __forceinline__ float gelu_f(float z) {
  float hz = 0.5f * z;
  return __builtin_fmaf(hz, erf_f(z * 0.70710678118654752f), hz);
}

__device__ __forceinline__ float exp_gelu(float z) { return __expf(gelu_f(z)); }

// ---------------- k1: h = x@W, Wh1/Wh2, hT(fp16) ----------------
__global__ __launch_bounds__(256, 2) void k1_proj(
    const float* __restrict__ x, const float* __restrict__ weight,
    const float* __restrict__ a, u16* __restrict__ hT,
    float* __restrict__ Wh1, float* __restrict__ Wh2)
{
  __shared__ float xs[32 * 256];     // 32 KB
  __shared__ float T[128 * 33];      // padded transpose buffer (16.9 KB)
  __shared__ float P2a[8 * 32], P2b[8 * 32];

  const int b = blockIdx.y, n0 = blockIdx.x * 32;
  const int tid = threadIdx.x;

  const float4* xsrc = (const float4*)(x + ((size_t)b * NN + n0) * DIN);
  float4* xd = (float4*)xs;
#pragma unroll
  for (int v = 0; v < 8; ++v) xd[tid + v * 256] = xsrc[tid + v * 256];
  __syncthreads();

  const int dg = tid & 31, rg = tid >> 5;
  float acc[4][4] = {};
  const float4* W4 = (const float4*)weight;
#pragma unroll 4
  for (int k = 0; k < 256; ++k) {
    float4 wr = W4[k * 32 + dg];
#pragma unroll
    for (int rr = 0; rr < 4; ++rr) {
      float xv = xs[(rg * 4 + rr) * 256 + k];
      acc[rr][0] = fmaf(xv, wr.x, acc[rr][0]);
      acc[rr][1] = fmaf(xv, wr.y, acc[rr][1]);
      acc[rr][2] = fmaf(xv, wr.z, acc[rr][2]);
      acc[rr][3] = fmaf(xv, wr.w, acc[rr][3]);
    }
  }
#pragma unroll
  for (int rr = 0; rr < 4; ++rr)
#pragma unroll
    for (int dd = 0; dd < 4; ++dd)
      T[(dg * 4 + dd) * 33 + rg * 4 + rr] = acc[rr][dd];
  __syncthreads();

  {
    const int d = tid & 127, half = tid >> 7;
    unsigned int uu[8];
#pragma unroll
    for (int p = 0; p < 8; ++p) {
      float f0 = T[d * 33 + half * 16 + p * 2];
      float f1 = T[d * 33 + half * 16 + p * 2 + 1];
      uu[p] = (unsigned int)f2h_bits(f0) | ((unsigned int)f2h_bits(f1) << 16);
    }
    u16* dst = hT + ((size_t)b * DOUT + d) * NN + n0 + half * 16;
    ((uint4*)dst)[0] = make_uint4(uu[0], uu[1], uu[2], uu[3]);
    ((uint4*)dst)[1] = make_uint4(uu[4], uu[5], uu[6], uu[7]);
  }
  {
    const int r = tid & 31, g8 = tid >> 5;
    float p1 = 0.f, p2 = 0.f;
#pragma unroll
    for (int q = 0; q < 16; ++q) {
      int d = g8 * 16 + q;
      float hv = T[d * 33 + r];
      p1 = fmaf(hv, a[d], p1);
      p2 = fmaf(hv, a[DOUT + d], p2);
    }
    P2a[g8 * 32 + r] = p1;
    P2b[g8 * 32 + r] = p2;
  }
  __syncthreads();
  if (tid < 32) {
    float s1 = 0.f, s2 = 0.f;
#pragma unroll
    for (int g8 = 0; g8 < 8; ++g8) { s1 += P2a[g8 * 32 + tid]; s2 += P2b[g8 * 32 + tid]; }
    Wh1[b * NN + n0 + tid] = s1;
    Wh2[b * NN + n0 + tid] = s2;
  }
}

// ---------------- k2: fused adj pass -> S_j + transposed bitmask ----------------
// grid (16 jt, 32 ic, BB) = 2048 blocks (8/CU -> HBM MLP saturated), block 256:
// thread = column j = jt*256+tid, 128 rows per thread (2 groups of 64).
// adj loads lane-consecutive 4 B (coalesced). Per 64-row group: 64 ballots
// accumulated into per-lane u64, then one coalesced store into transposed
// planes m32[b][jw][i].
__global__ __launch_bounds__(256) void k2_fused(
    const int* __restrict__ adj, const float* __restrict__ Wh1,
    const float* __restrict__ Wh2, float* __restrict__ S,
    unsigned int* __restrict__ m32)
{
  const int b = blockIdx.z, jt = blockIdx.x, ic = blockIdx.y;
  const int tid = threadIdx.x;
  const int j = jt * 256 + tid;
  const int lane = tid & 63;
  const int jg = jt * 4 + (tid >> 6);      // global 64-j group
  const int i0 = ic * 128;

  const float wh2 = Wh2[b * NN + j];
  const int* ap = adj + ((size_t)b * NN + i0) * NN + j;
  const float* w1p = Wh1 + b * NN + i0;
  unsigned int* mlo = m32 + ((size_t)b * 128 + jg * 2) * NN + i0;
  unsigned int* mhi = mlo + NN;

  float s = 0.f;
  for (int g = 0; g < 2; ++g) {            // 2 groups of 64 rows
    unsigned long long acc64 = 0ull;
#pragma unroll
    for (int gg = 0; gg < 8; ++gg) {       // 8 sub-batches of 8 rows
      int av[8]; float w1v[8];
#pragma unroll
      for (int k = 0; k < 8; ++k) {
        const int ii = g * 64 + gg * 8 + k;
        av[k]  = ap[(size_t)ii * NN];
        w1v[k] = w1p[ii];                  // block-uniform -> scalar load
      }
#pragma unroll
      for (int k = 0; k < 8; ++k) {
        const unsigned long long bal = __ballot(av[k] > 0);
        if (lane == gg * 8 + k) acc64 = bal;   // cndmask keep
        const float E = exp_gelu(w1v[k] + wh2);
        s += (av[k] > 0) ? E : 0.f;
      }
    }
    mlo[g * 64 + lane] = (unsigned int)acc64;          // coalesced 256 B
    mhi[g * 64 + lane] = (unsigned int)(acc64 >> 32);  // coalesced 256 B
  }
  atomicAdd(&S[b * NN + j], s);
}

__global__ __launch_bounds__(256) void k25_rcp(const float* __restrict__ S,
                                               float* __restrict__ Sinv)
{
  int id = blockIdx.x * 256 + threadIdx.x;
  Sinv[id] = 1.0f / S[id];     // all-masked column cannot occur (p=0.5, N=4096)
}

// ---------------- k3: out_pre = P @ h via fp16 MFMA ----------------
// grid (NN/32, BB) = 512 blocks, block 512 = 8 waves; block covers 32 rows.
// Wave w owns j in [w*512, +512) (8-way K-split) and a private 8 KB LDS
// buffer; the staged B-tile feeds TWO A-row-tiles. Waves = 4096 = 4/SIMD,
// L2 traffic = 512 blocks x 1 MB = 512 MB. No __syncthreads in the K-loop.
// Staging: coalesced global_load_lds width=16 (lane l -> LDS base + l*16 B);
// one DMA inst = 64 lanes x 16 B = 512 u16 -> inst stride 512 u16.
__global__ __launch_bounds__(512, 4) void k3_attn(
    const unsigned int* __restrict__ m32, const float* __restrict__ Wh1,
    const float* __restrict__ Wh2, const float* __restrict__ Sinv,
    const u16* __restrict__ hT, float* __restrict__ out_pre)
{
  __shared__ __align__(16) u16 buf[8][128 * 32];   // 8 waves x 8 KB = 64 KB

  const int b = blockIdx.y;
  const int i0 = blockIdx.x * 32;
  const int tid = threadIdx.x;
  const int w = tid >> 6, lane = tid & 63;
  const int m = lane & 15, quad = lane >> 4;

  const float w1a = Wh1[b * NN + i0 + m];
  const float w1b = Wh1[b * NN + i0 + 16 + m];
  const unsigned int* mbase = m32 + (size_t)b * 128 * NN;
  const u16* hTb = hT + (size_t)b * DOUT * NN;
  // staging: lane l covers row (l>>2)+inst*16, j-offset (l&3)*8 -> LDS u16 ofs l*8
  const u16* srcbase = hTb + (size_t)(lane >> 2) * NN + (lane & 3) * 8;

  f32x4 acc0[8], acc1[8];
#pragma unroll
  for (int t = 0; t < 8; ++t) {
    acc0[t] = (f32x4){0.f, 0.f, 0.f, 0.f};
    acc1[t] = (f32x4){0.f, 0.f, 0.f, 0.f};
  }

  for (int c = 0; c < 16; ++c) {
    const int j0 = w * 512 + c * 32;
    const int jw = j0 >> 5;

    // WAR: previous chunk's ds_reads must complete before DMA overwrites LDS
    __builtin_amdgcn_s_waitcnt(0xC07F);   // lgkmcnt(0) only
#pragma unroll
    for (int inst = 0; inst < 8; ++inst) {
      const u16* g = srcbase + (size_t)inst * 16 * NN + j0;
      __builtin_amdgcn_global_load_lds(
          (const __attribute__((address_space(1))) void*)g,
          (__attribute__((address_space(3))) void*)&buf[w][inst * 512],
          16, 0, 0);
    }

    // masks for both row-tiles (transposed planes, coalesced over m)
    const unsigned int Ma = mbase[(size_t)jw * NN + i0 + m];
    const unsigned int Mb = mbase[(size_t)jw * NN + i0 + 16 + m];
    const unsigned int mba = (Ma >> (quad * 8)) & 0xFFu;
    const unsigned int mbb = (Mb >> (quad * 8)) & 0xFFu;

    const int jq = j0 + quad * 8;
    const float4* wp = (const float4*)(Wh2 + b * NN + jq);
    float4 w2a = wp[0], w2b = wp[1];
    const float4* sp = (const float4*)(Sinv + b * NN + jq);
    float4 sva = sp[0], svb = sp[1];

    float q[8];
    f16x8 ah_a, al_a, ah_b, al_b;

    // row-tile a (rows i0..i0+15)
    q[0] = (mba & 1u)   ? exp_gelu(w1a + w2a.x) * sva.x : 0.f;
    q[1] = (mba & 2u)   ? exp_gelu(w1a + w2a.y) * sva.y : 0.f;
    q[2] = (mba & 4u)   ? exp_gelu(w1a + w2a.z) * sva.z : 0.f;
    q[3] = (mba & 8u)   ? exp_gelu(w1a + w2a.w) * sva.w : 0.f;
    q[4] = (mba & 16u)  ? exp_gelu(w1a + w2b.x) * svb.x : 0.f;
    q[5] = (mba & 32u)  ? exp_gelu(w1a + w2b.y) * svb.y : 0.f;
    q[6] = (mba & 64u)  ? exp_gelu(w1a + w2b.z) * svb.z : 0.f;
    q[7] = (mba & 128u) ? exp_gelu(w1a + w2b.w) * svb.w : 0.f;
#pragma unroll
    for (int e = 0; e < 8; ++e) {
      _Float16 hi = (_Float16)q[e];
      ah_a[e] = hi;
      al_a[e] = (_Float16)(q[e] - (float)hi);
    }
    // row-tile b (rows i0+16..i0+31)
    q[0] = (mbb & 1u)   ? exp_gelu(w1b + w2a.x) * sva.x : 0.f;
    q[1] = (mbb & 2u)   ? exp_gelu(w1b + w2a.y) * sva.y : 0.f;
    q[2] = (mbb & 4u)   ? exp_gelu(w1b + w2a.z) * sva.z : 0.f;
    q[3] = (mbb & 8u)   ? exp_gelu(w1b + w2a.w) * sva.w : 0.f;
    q[4] = (mbb & 16u)  ? exp_gelu(w1b + w2b.x) * svb.x : 0.f;
    q[5] = (mbb & 32u)  ? exp_gelu(w1b + w2b.y) * svb.y : 0.f;
    q[6] = (mbb & 64u)  ? exp_gelu(w1b + w2b.z) * svb.z : 0.f;
    q[7] = (mbb & 128u) ? exp_gelu(w1b + w2b.w) * svb.w : 0.f;
#pragma unroll
    for (int e = 0; e < 8; ++e) {
      _Float16 hi = (_Float16)q[e];
      ah_b[e] = hi;
      al_b[e] = (_Float16)(q[e] - (float)hi);
    }

    // drain the DMA before reading LDS
    __builtin_amdgcn_s_waitcnt(0x0F70);   // vmcnt(0) only

#pragma unroll
    for (int t = 0; t < 8; ++t) {
      f16x8 bf = *(const f16x8*)&buf[w][(t * 16 + m) * 32 + quad * 8];
      acc0[t] = __builtin_amdgcn_mfma_f32_16x16x32_f16(ah_a, bf, acc0[t], 0, 0, 0);
      acc0[t] = __builtin_amdgcn_mfma_f32_16x16x32_f16(al_a, bf, acc0[t], 0, 0, 0);
      acc1[t] = __builtin_amdgcn_mfma_f32_16x16x32_f16(ah_b, bf, acc1[t], 0, 0, 0);
      acc1[t] = __builtin_amdgcn_mfma_f32_16x16x32_f16(al_b, bf, acc1[t], 0, 0, 0);
    }
  }

  // 8-way K-split reduce, two passes (row-tile 0 then 1).
  // red needs 8 waves x 2048 floats = 64 KB = exactly buf.
  float* red = (float*)&buf[0][0];
#pragma unroll
  for (int rt = 0; rt < 2; ++rt) {
    __syncthreads();
#pragma unroll
    for (int t = 0; t < 8; ++t)
#pragma unroll
      for (int r = 0; r < 4; ++r)
        red[w * 2048 + (t * 4 + r) * 64 + lane] = rt ? acc1[t][r] : acc0[t][r];
    __syncthreads();
    // wave w finalizes d-tile t = w (C layout: row=quad*4+r, col=t*16+m)
#pragma unroll
    for (int r = 0; r < 4; ++r) {
      const int o = (w * 4 + r) * 64 + lane;
      float v = 0.f;
#pragma unroll
      for (int wk = 0; wk < 8; ++wk) v += red[wk * 2048 + o];
      out_pre[((size_t)b * NN + i0 + rt * 16 + quad * 4 + r) * DOUT + w * 16 + m] = v;
    }
  }
}

// ---------------- k4a: gelu + column sum-of-squares ----------------
__global__ __launch_bounds__(256) void k4a_gelu_norm(
    const float* __restrict__ out_pre, float* __restrict__ gout,
    float* __restrict__ norm2)
{
  __shared__ float pbuf[256];
  const int b = blockIdx.y;
  const int i0 = blockIdx.x * 64;
  const int tid = threadIdx.x;
  const int d = tid & 127, rh = tid >> 7;
  float acc = 0.f;
  for (int ii = rh; ii < 64; ii += 2) {
    size_t idx = ((size_t)b * NN + i0 + ii) * DOUT + d;
    float g = gelu_f(out_pre[idx]);
    gout[idx] = g;
    acc = fmaf(g, g, acc);
  }
  pbuf[tid] = acc;
  __syncthreads();
  if (tid < 128) atomicAdd(&norm2[b * DOUT + tid], pbuf[tid] + pbuf[tid + 128]);
}

// ---------------- k4b: scale by 1/max(||col||,1e-12) + bias ----------------
__global__ __launch_bounds__(256) void k4b_scale(
    float* __restrict__ out, const float* __restrict__ norm2,
    const float* __restrict__ bias)
{
  int id = blockIdx.x * 256 + threadIdx.x;
  int d = id & 127;
  int b = id >> 19;                        // N*DOUT = 2^19 per batch
  float nrm = sqrtf(norm2[b * DOUT + d]);
  float sc = 1.0f / fmaxf(nrm, 1e-12f);
  out[id] = fmaf(out[id], sc, bias[d]);
}

extern "C" void kernel_launch(void* const* d_in, const int* in_sizes, int n_in,
                              void* d_out, int out_size, void* d_ws, size_t ws_size,
                              hipStream_t stream)
{
  const float* x      = (const float*)d_in[0];
  const int*   adj    = (const int*)d_in[1];
  const float* weight = (const float*)d_in[2];
  const float* a      = (const float*)d_in[3];
  const float* bias   = (const float*)d_in[4];
  float* out = (float*)d_out;

  // workspace layout (all 16B aligned), ~21.3 MB total
  char* ws = (char*)d_ws;
  u16*   hT     = (u16*)ws;                                    // 4 MB
  float* Wh1    = (float*)(ws + (size_t)4 * 1024 * 1024);      // 64 KB
  float* Wh2    = Wh1 + BB * NN;                               // 64 KB
  float* S      = Wh2 + BB * NN;                               // 64 KB
  float* Sinv   = S + BB * NN;                                 // 64 KB
  unsigned int* m32 = (unsigned int*)(Sinv + BB * NN);         // 8 MB, [b][128][4096]
  float* out_pre = (float*)((char*)m32 + (size_t)BB * 128 * NN * 4); // 8 MB
  float* norm2   = out_pre + (size_t)BB * NN * DOUT;           // 2 KB

  hipMemsetAsync(S, 0, (size_t)BB * NN * sizeof(float), stream);
  hipMemsetAsync(norm2, 0, (size_t)BB * DOUT * sizeof(float), stream);

  k1_proj<<<dim3(NN / 32, BB), 256, 0, stream>>>(x, weight, a, hT, Wh1, Wh2);
  k2_fused<<<dim3(16, 32, BB), 256, 0, stream>>>(adj, Wh1, Wh2, S, m32);
  k25_rcp<<<dim3(BB * NN / 256), 256, 0, stream>>>(S, Sinv);
  k3_attn<<<dim3(NN / 32, BB), 512, 0, stream>>>(m32, Wh1, Wh2, Sinv, hT, out_pre);
  k4a_gelu_norm<<<dim3(64, BB), 256, 0, stream>>>(out_pre, out, norm2);
  k4b_scale<<<dim3((BB * NN * DOUT) / 256), 256, 0, stream>>>(out, norm2, bias);
}

// Round 8
// 506.580 us; speedup vs baseline: 1.3397x; 1.0067x over previous
//
#include <hip/hip_runtime.h>
#include <hip/hip_bf16.h>
#include <stdint.h>

// GAT-style attention layer, B=4 N=4096 Din=256 Dout=128, fp32 in/out.
// Pipeline:
//  k1 : h = x@W (fp32), store hT (fp16, [b][d][n]) + Wh1/Wh2 = h@a (fp32)
//  k2 : ONE coalesced pass over adj: S_j (atomicAdd) + transposed bitmask
//       m32[b][jw][i]; 16-deep load batches
//  k25: Sinv = 1/S
//  k3 : out = gelu(P @ h), fp16 MFMA (single-precision A, no hi/lo split);
//       256-thr blocks, 4-way K-split, 32 rows/block; fused epilogue does
//       gelu + norm2 (sum of squares per column) atomics
//  k4b: L2-normalize over i + bias
//
// R7 lesson: __launch_bounds__(512,4) capped VGPRs at 128 (borderline ->
// possible spill); occupancy past 2 waves/SIMD buys nothing because each
// wave is ~83% VALU-dense. Stick to 256-thr / cap-256.

#define NN   4096
#define BB   4
#define DIN  256
#define DOUT 128

typedef unsigned short u16;
typedef _Float16 f16x8 __attribute__((ext_vector_type(8)));
typedef __attribute__((ext_vector_type(4))) float f32x4;

__device__ __forceinline__ u16 f2h_bits(float f) {
  _Float16 h = (_Float16)f;          // v_cvt_f16_f32, RNE
  union { _Float16 h; u16 u; } v; v.h = h;
  return v.u;
}

// Abramowitz-Stegun 7.1.26, |err| < 1.5e-7
__device__ __forceinline__ float erf_f(float x) {
  float ax = __builtin_fabsf(x);
  float t  = __builtin_amdgcn_rcpf(__builtin_fmaf(0.3275911f, ax, 1.0f));
  float p  = __builtin_fmaf(1.061405429f, t, -1.453152027f);
  p = __builtin_fmaf(p, t, 1.421413741f);
  p = __builtin_fmaf(p, t, -0.284496736f);
  p = __builtin_fmaf(p, t, 0.254829592f);
  p = p * t;
  float e  = __expf(-ax * ax);
  float er = __builtin_fmaf(-p, e, 1.0f);
  return copysignf(er, x);
}

__device__ __forceinline__ float gelu_f(float z) {
  float hz = 0.5f * z;
  return __builtin_fmaf(hz, erf_f(z * 0.70710678118654752f), hz);
}

__device__ __forceinline__ float exp_gelu(float z) { return __expf(gelu_f(z)); }

// ---------------- k1: h = x@W, Wh1/Wh2, hT(fp16) ----------------
__global__ __launch_bounds__(256, 2) void k1_proj(
    const float* __restrict__ x, const float* __restrict__ weight,
    const float* __restrict__ a, u16* __restrict__ hT,
    float* __restrict__ Wh1, float* __restrict__ Wh2)
{
  __shared__ float xs[32 * 256];     // 32 KB
  __shared__ float T[128 * 33];      // padded transpose buffer (16.9 KB)
  __shared__ float P2a[8 * 32], P2b[8 * 32];

  const int b = blockIdx.y, n0 = blockIdx.x * 32;
  const int tid = threadIdx.x;

  const float4* xsrc = (const float4*)(x + ((size_t)b * NN + n0) * DIN);
  float4* xd = (float4*)xs;
#pragma unroll
  for (int v = 0; v < 8; ++v) xd[tid + v * 256] = xsrc[tid + v * 256];
  __syncthreads();

  const int dg = tid & 31, rg = tid >> 5;
  float acc[4][4] = {};
  const float4* W4 = (const float4*)weight;
#pragma unroll 4
  for (int k = 0; k < 256; ++k) {
    float4 wr = W4[k * 32 + dg];
#pragma unroll
    for (int rr = 0; rr < 4; ++rr) {
      float xv = xs[(rg * 4 + rr) * 256 + k];
      acc[rr][0] = fmaf(xv, wr.x, acc[rr][0]);
      acc[rr][1] = fmaf(xv, wr.y, acc[rr][1]);
      acc[rr][2] = fmaf(xv, wr.z, acc[rr][2]);
      acc[rr][3] = fmaf(xv, wr.w, acc[rr][3]);
    }
  }
#pragma unroll
  for (int rr = 0; rr < 4; ++rr)
#pragma unroll
    for (int dd = 0; dd < 4; ++dd)
      T[(dg * 4 + dd) * 33 + rg * 4 + rr] = acc[rr][dd];
  __syncthreads();

  {
    const int d = tid & 127, half = tid >> 7;
    unsigned int uu[8];
#pragma unroll
    for (int p = 0; p < 8; ++p) {
      float f0 = T[d * 33 + half * 16 + p * 2];
      float f1 = T[d * 33 + half * 16 + p * 2 + 1];
      uu[p] = (unsigned int)f2h_bits(f0) | ((unsigned int)f2h_bits(f1) << 16);
    }
    u16* dst = hT + ((size_t)b * DOUT + d) * NN + n0 + half * 16;
    ((uint4*)dst)[0] = make_uint4(uu[0], uu[1], uu[2], uu[3]);
    ((uint4*)dst)[1] = make_uint4(uu[4], uu[5], uu[6], uu[7]);
  }
  {
    const int r = tid & 31, g8 = tid >> 5;
    float p1 = 0.f, p2 = 0.f;
#pragma unroll
    for (int q = 0; q < 16; ++q) {
      int d = g8 * 16 + q;
      float hv = T[d * 33 + r];
      p1 = fmaf(hv, a[d], p1);
      p2 = fmaf(hv, a[DOUT + d], p2);
    }
    P2a[g8 * 32 + r] = p1;
    P2b[g8 * 32 + r] = p2;
  }
  __syncthreads();
  if (tid < 32) {
    float s1 = 0.f, s2 = 0.f;
#pragma unroll
    for (int g8 = 0; g8 < 8; ++g8) { s1 += P2a[g8 * 32 + tid]; s2 += P2b[g8 * 32 + tid]; }
    Wh1[b * NN + n0 + tid] = s1;
    Wh2[b * NN + n0 + tid] = s2;
  }
}

// ---------------- k2: fused adj pass -> S_j + transposed bitmask ----------------
// grid (16 jt, 32 ic, BB) = 2048 blocks, block 256: thread = column
// j = jt*256+tid, 128 rows per thread. adj loads lane-consecutive 4 B
// (coalesced), batched 16-deep for outstanding-load depth. Per 64-row group:
// 64 ballots accumulated into per-lane u64, one coalesced store into
// transposed planes m32[b][jw][i].
__global__ __launch_bounds__(256) void k2_fused(
    const int* __restrict__ adj, const float* __restrict__ Wh1,
    const float* __restrict__ Wh2, float* __restrict__ S,
    unsigned int* __restrict__ m32)
{
  const int b = blockIdx.z, jt = blockIdx.x, ic = blockIdx.y;
  const int tid = threadIdx.x;
  const int j = jt * 256 + tid;
  const int lane = tid & 63;
  const int jg = jt * 4 + (tid >> 6);      // global 64-j group
  const int i0 = ic * 128;

  const float wh2 = Wh2[b * NN + j];
  const int* ap = adj + ((size_t)b * NN + i0) * NN + j;
  const float* w1p = Wh1 + b * NN + i0;
  unsigned int* mlo = m32 + ((size_t)b * 128 + jg * 2) * NN + i0;
  unsigned int* mhi = mlo + NN;

  float s = 0.f;
  for (int g = 0; g < 2; ++g) {            // 2 groups of 64 rows
    unsigned long long acc64 = 0ull;
#pragma unroll
    for (int gg = 0; gg < 4; ++gg) {       // 4 sub-batches of 16 rows
      int av[16]; float w1v[16];
#pragma unroll
      for (int k = 0; k < 16; ++k) {
        const int ii = g * 64 + gg * 16 + k;
        av[k]  = ap[(size_t)ii * NN];
        w1v[k] = w1p[ii];                  // block-uniform -> scalar load
      }
#pragma unroll
      for (int k = 0; k < 16; ++k) {
        const unsigned long long bal = __ballot(av[k] > 0);
        if (lane == gg * 16 + k) acc64 = bal;   // cndmask keep
        const float E = exp_gelu(w1v[k] + wh2);
        s += (av[k] > 0) ? E : 0.f;
      }
    }
    mlo[g * 64 + lane] = (unsigned int)acc64;          // coalesced 256 B
    mhi[g * 64 + lane] = (unsigned int)(acc64 >> 32);  // coalesced 256 B
  }
  atomicAdd(&S[b * NN + j], s);
}

__global__ __launch_bounds__(256) void k25_rcp(const float* __restrict__ S,
                                               float* __restrict__ Sinv)
{
  int id = blockIdx.x * 256 + threadIdx.x;
  Sinv[id] = 1.0f / S[id];     // all-masked column cannot occur (p=0.5, N=4096)
}

// ---------------- k3: out = gelu(P @ h) via fp16 MFMA + fused norm2 ----------------
// grid (NN/32, BB) = 512 blocks, block 256 = 4 waves; block covers 32 rows.
// Wave w owns j in [w*1024, +1024) (4-way K-split), private 8 KB LDS buffer,
// staged B-tile feeds TWO A-row-tiles. No __syncthreads in the K-loop.
// A-operand: single fp16 (no hi/lo split) — h's fp16 error dominates anyway.
// Epilogue: K-split reduce, gelu, write d_out, per-block norm2 atomics.
__global__ __launch_bounds__(256, 2) void k3_attn(
    const unsigned int* __restrict__ m32, const float* __restrict__ Wh1,
    const float* __restrict__ Wh2, const float* __restrict__ Sinv,
    const u16* __restrict__ hT, float* __restrict__ out,
    float* __restrict__ norm2)
{
  __shared__ __align__(16) u16 buf[4][128 * 32];   // 4 waves x 8 KB = 32 KB

  const int b = blockIdx.y;
  const int i0 = blockIdx.x * 32;
  const int tid = threadIdx.x;
  const int w = tid >> 6, lane = tid & 63;
  const int m = lane & 15, quad = lane >> 4;

  const float w1a = Wh1[b * NN + i0 + m];
  const float w1b = Wh1[b * NN + i0 + 16 + m];
  const unsigned int* mbase = m32 + (size_t)b * 128 * NN;
  const u16* hTb = hT + (size_t)b * DOUT * NN;
  // staging: lane l covers row (l>>2)+inst*16, j-offset (l&3)*8 -> LDS u16 ofs l*8
  const u16* srcbase = hTb + (size_t)(lane >> 2) * NN + (lane & 3) * 8;

  f32x4 acc0[8], acc1[8];
#pragma unroll
  for (int t = 0; t < 8; ++t) {
    acc0[t] = (f32x4){0.f, 0.f, 0.f, 0.f};
    acc1[t] = (f32x4){0.f, 0.f, 0.f, 0.f};
  }

  for (int c = 0; c < 32; ++c) {
    const int j0 = w * 1024 + c * 32;
    const int jw = j0 >> 5;

    // WAR: previous chunk's ds_reads must complete before DMA overwrites LDS
    __builtin_amdgcn_s_waitcnt(0xC07F);   // lgkmcnt(0) only
#pragma unroll
    for (int inst = 0; inst < 8; ++inst) {
      const u16* g = srcbase + (size_t)inst * 16 * NN + j0;
      __builtin_amdgcn_global_load_lds(
          (const __attribute__((address_space(1))) void*)g,
          (__attribute__((address_space(3))) void*)&buf[w][inst * 512],
          16, 0, 0);
    }

    // masks for both row-tiles (transposed planes, coalesced over m)
    const unsigned int Ma = mbase[(size_t)jw * NN + i0 + m];
    const unsigned int Mb = mbase[(size_t)jw * NN + i0 + 16 + m];
    const unsigned int mba = (Ma >> (quad * 8)) & 0xFFu;
    const unsigned int mbb = (Mb >> (quad * 8)) & 0xFFu;

    const int jq = j0 + quad * 8;
    const float4* wp = (const float4*)(Wh2 + b * NN + jq);
    float4 w2a = wp[0], w2b = wp[1];
    const float4* sp = (const float4*)(Sinv + b * NN + jq);
    float4 sva = sp[0], svb = sp[1];

    f16x8 ah_a, ah_b;
    // row-tile a (rows i0..i0+15)
    ah_a[0] = (_Float16)((mba & 1u)   ? exp_gelu(w1a + w2a.x) * sva.x : 0.f);
    ah_a[1] = (_Float16)((mba & 2u)   ? exp_gelu(w1a + w2a.y) * sva.y : 0.f);
    ah_a[2] = (_Float16)((mba & 4u)   ? exp_gelu(w1a + w2a.z) * sva.z : 0.f);
    ah_a[3] = (_Float16)((mba & 8u)   ? exp_gelu(w1a + w2a.w) * sva.w : 0.f);
    ah_a[4] = (_Float16)((mba & 16u)  ? exp_gelu(w1a + w2b.x) * svb.x : 0.f);
    ah_a[5] = (_Float16)((mba & 32u)  ? exp_gelu(w1a + w2b.y) * svb.y : 0.f);
    ah_a[6] = (_Float16)((mba & 64u)  ? exp_gelu(w1a + w2b.z) * svb.z : 0.f);
    ah_a[7] = (_Float16)((mba & 128u) ? exp_gelu(w1a + w2b.w) * svb.w : 0.f);
    // row-tile b (rows i0+16..i0+31)
    ah_b[0] = (_Float16)((mbb & 1u)   ? exp_gelu(w1b + w2a.x) * sva.x : 0.f);
    ah_b[1] = (_Float16)((mbb & 2u)   ? exp_gelu(w1b + w2a.y) * sva.y : 0.f);
    ah_b[2] = (_Float16)((mbb & 4u)   ? exp_gelu(w1b + w2a.z) * sva.z : 0.f);
    ah_b[3] = (_Float16)((mbb & 8u)   ? exp_gelu(w1b + w2a.w) * sva.w : 0.f);
    ah_b[4] = (_Float16)((mbb & 16u)  ? exp_gelu(w1b + w2b.x) * svb.x : 0.f);
    ah_b[5] = (_Float16)((mbb & 32u)  ? exp_gelu(w1b + w2b.y) * svb.y : 0.f);
    ah_b[6] = (_Float16)((mbb & 64u)  ? exp_gelu(w1b + w2b.z) * svb.z : 0.f);
    ah_b[7] = (_Float16)((mbb & 128u) ? exp_gelu(w1b + w2b.w) * svb.w : 0.f);

    // drain the DMA before reading LDS
    __builtin_amdgcn_s_waitcnt(0x0F70);   // vmcnt(0) only

#pragma unroll
    for (int t = 0; t < 8; ++t) {
      f16x8 bf = *(const f16x8*)&buf[w][(t * 16 + m) * 32 + quad * 8];
      acc0[t] = __builtin_amdgcn_mfma_f32_16x16x32_f16(ah_a, bf, acc0[t], 0, 0, 0);
      acc1[t] = __builtin_amdgcn_mfma_f32_16x16x32_f16(ah_b, bf, acc1[t], 0, 0, 0);
    }
  }

  // 4-way K-split reduce (red = 4 x 2048 fp32 = 32 KB = buf), two passes.
  // Fused epilogue: gelu -> out, accumulate per-d sum of squares.
  float* red = (float*)&buf[0][0];
  float p2[2] = {0.f, 0.f};
#pragma unroll
  for (int rt = 0; rt < 2; ++rt) {
    __syncthreads();
#pragma unroll
    for (int t = 0; t < 8; ++t)
#pragma unroll
      for (int r = 0; r < 4; ++r)
        red[w * 2048 + (t * 4 + r) * 64 + lane] = rt ? acc1[t][r] : acc0[t][r];
    __syncthreads();
    // wave w finalizes d-tiles t = 2w, 2w+1 (C layout: row=quad*4+r, col=t*16+m)
#pragma unroll
    for (int tt = 0; tt < 2; ++tt) {
      const int t = w * 2 + tt;
#pragma unroll
      for (int r = 0; r < 4; ++r) {
        const int o = (t * 4 + r) * 64 + lane;
        float v = red[o] + red[2048 + o] + red[4096 + o] + red[6144 + o];
        float gv = gelu_f(v);
        out[((size_t)b * NN + i0 + rt * 16 + quad * 4 + r) * DOUT + t * 16 + m] = gv;
        p2[tt] = fmaf(gv, gv, p2[tt]);
      }
    }
  }
  // cross-quad reduce (lanes m, m+16, m+32, m+48 share d), one atomic per d
#pragma unroll
  for (int tt = 0; tt < 2; ++tt) {
    float ps = p2[tt];
    ps += __shfl_xor(ps, 16);
    ps += __shfl_xor(ps, 32);
    if (quad == 0)
      atomicAdd(&norm2[b * DOUT + (w * 2 + tt) * 16 + m], ps);
  }
}

// ---------------- k4b: scale by 1/max(||col||,1e-12) + bias ----------------
__global__ __launch_bounds__(256) void k4b_scale(
    float* __restrict__ out, const float* __restrict__ norm2,
    const float* __restrict__ bias)
{
  int id = blockIdx.x * 256 + threadIdx.x;
  int d = id & 127;
  int b = id >> 19;                        // N*DOUT = 2^19 per batch
  float nrm = sqrtf(norm2[b * DOUT + d]);
  float sc = 1.0f / fmaxf(nrm, 1e-12f);
  out[id] = fmaf(out[id], sc, bias[d]);
}

extern "C" void kernel_launch(void* const* d_in, const int* in_sizes, int n_in,
                              void* d_out, int out_size, void* d_ws, size_t ws_size,
                              hipStream_t stream)
{
  const float* x      = (const float*)d_in[0];
  const int*   adj    = (const int*)d_in[1];
  const float* weight = (const float*)d_in[2];
  const float* a      = (const float*)d_in[3];
  const float* bias   = (const float*)d_in[4];
  float* out = (float*)d_out;

  // workspace layout (all 16B aligned), ~12.3 MB total
  char* ws = (char*)d_ws;
  u16*   hT     = (u16*)ws;                                    // 4 MB
  float* Wh1    = (float*)(ws + (size_t)4 * 1024 * 1024);      // 64 KB
  float* Wh2    = Wh1 + BB * NN;                               // 64 KB
  float* S      = Wh2 + BB * NN;                               // 64 KB
  float* Sinv   = S + BB * NN;                                 // 64 KB
  unsigned int* m32 = (unsigned int*)(Sinv + BB * NN);         // 8 MB, [b][128][4096]
  float* norm2  = (float*)((char*)m32 + (size_t)BB * 128 * NN * 4);  // 2 KB

  hipMemsetAsync(S, 0, (size_t)BB * NN * sizeof(float), stream);
  hipMemsetAsync(norm2, 0, (size_t)BB * DOUT * sizeof(float), stream);

  k1_proj<<<dim3(NN / 32, BB), 256, 0, stream>>>(x, weight, a, hT, Wh1, Wh2);
  k2_fused<<<dim3(16, 32, BB), 256, 0, stream>>>(adj, Wh1, Wh2, S, m32);
  k25_rcp<<<dim3(BB * NN / 256), 256, 0, stream>>>(S, Sinv);
  k3_attn<<<dim3(NN / 32, BB), 256, 0, stream>>>(m32, Wh1, Wh2, Sinv, hT, out, norm2);
  k4b_scale<<<dim3((BB * NN * DOUT) / 256), 256, 0, stream>>>(out, norm2, bias);
}